// Round 1
// baseline (2280.968 us; speedup 1.0000x reference)
//
#include <hip/hip_runtime.h>
#include <math.h>

#define NN 8192
#define EE 131072
#define ELn 139264   // EE + NN (edges + self loops)
#define HH 128
#define KK 4096

__device__ __forceinline__ int esrc(const int* __restrict__ edges, int e){ return e < EE ? edges[e] : e - EE; }
__device__ __forceinline__ int edst(const int* __restrict__ edges, int e){ return e < EE ? edges[EE + e] : e - EE; }

// ---------- degree / CSR-by-dst ----------
__global__ void k_count_indeg(const int* __restrict__ edges, int* __restrict__ deg){
  int e = blockIdx.x*blockDim.x + threadIdx.x;
  if (e < ELn) atomicAdd(&deg[edst(edges,e)], 1);
}

__global__ void k_dis(const int* __restrict__ deg, float* __restrict__ dis){
  int v = blockIdx.x*blockDim.x + threadIdx.x;
  if (v < NN){ float d = (float)deg[v]; d = d < 1.0f ? 1.0f : d; dis[v] = 1.0f/sqrtf(d); }
}

// single-block exclusive scan over NN counts -> rowptr[NN+1], cursor copy
__global__ __launch_bounds__(1024) void k_scan(const int* __restrict__ cnt, int* __restrict__ rowptr, int* __restrict__ cur){
  __shared__ int part[1024];
  int tid = threadIdx.x;
  int base = tid*8;
  int loc[8]; int s=0;
  #pragma unroll
  for (int i=0;i<8;i++) loc[i]=cnt[base+i];
  #pragma unroll
  for (int i=0;i<8;i++){ int t=loc[i]; loc[i]=s; s+=t; }
  part[tid]=s;
  __syncthreads();
  for (int off=1; off<1024; off<<=1){
    int v = (tid>=off)? part[tid-off] : 0;
    __syncthreads();
    part[tid]+=v;
    __syncthreads();
  }
  int cb = part[tid]-s;   // exclusive base of this chunk
  #pragma unroll
  for (int i=0;i<8;i++){ int r=cb+loc[i]; rowptr[base+i]=r; cur[base+i]=r; }
  if (tid==1023) rowptr[NN]=part[1023];
}

__global__ void k_fill_dst(const int* __restrict__ edges, int* __restrict__ cur, int* __restrict__ delist){
  int e = blockIdx.x*blockDim.x + threadIdx.x;
  if (e < ELn){ int v = edst(edges,e); int pos=atomicAdd(&cur[v],1); delist[pos]=e; }
}

// ---------- small fp32 GEMM: y[NNxHH] = x[NNxHH] @ W[HHxHH] (+bias) ----------
__global__ __launch_bounds__(256) void k_gemm128(const float* __restrict__ x, const float* __restrict__ W,
                          const float* __restrict__ bias, float* __restrict__ y){
  __shared__ float Wl[HH*HH];
  int tid = threadIdx.x;
  for (int i=tid;i<HH*HH;i+=256) Wl[i]=W[i];
  __syncthreads();
  int c = tid & 127, rh = tid >> 7;
  int r0 = blockIdx.x*32;
  float bc = bias ? bias[c] : 0.0f;
  for (int rp=0; rp<16; ++rp){
    int r = r0 + rp*2 + rh;
    const float* xr = x + (size_t)r*HH;
    float acc = bc;
    #pragma unroll
    for (int k=0;k<HH;k+=4){
      float4 xv = *(const float4*)(xr+k);
      acc += xv.x*Wl[(k+0)*HH+c];
      acc += xv.y*Wl[(k+1)*HH+c];
      acc += xv.z*Wl[(k+2)*HH+c];
      acc += xv.w*Wl[(k+3)*HH+c];
    }
    y[(size_t)r*HH+c]=acc;
  }
}

// ---------- GCN scatter: out[v] = (tanh?)(bias + dis[v]*sum_in y[src]*dis[src]) ----------
template<int TANH>
__global__ void k_gcn_scatter(const float* __restrict__ y, const int* __restrict__ edges,
    const int* __restrict__ drowptr, const int* __restrict__ delist,
    const float* __restrict__ dis, const float* __restrict__ bias, float* __restrict__ out){
  int v = blockIdx.x, f = threadIdx.x;
  int beg = drowptr[v], end = drowptr[v+1];
  float acc = 0.0f;
  for (int i=beg;i<end;++i){
    int e = delist[i]; int u = esrc(edges,e);
    acc += y[(size_t)u*HH+f]*dis[u];
  }
  acc = acc*dis[v] + bias[f];
  if (TANH) acc = tanhf(acc);
  out[(size_t)v*HH+f] = acc;
}

// ---------- segment max over in-edges ----------
__global__ void k_segmax(const float* __restrict__ h, const int* __restrict__ edges,
    const int* __restrict__ drowptr, const int* __restrict__ delist, float* __restrict__ out){
  int v = blockIdx.x, f = threadIdx.x;
  int beg = drowptr[v], end = drowptr[v+1];
  float m = -3.4e38f;
  for (int i=beg;i<end;++i){
    int e = delist[i]; int u = esrc(edges,e);
    m = fmaxf(m, h[(size_t)u*HH+f]);
  }
  out[(size_t)v*HH+f] = m;
}

// ---------- attention dots: aq[v]=xq[v].att[:H], ah[v]=h[v].att[H:] ----------
__global__ void k_aqah(const float* __restrict__ xq, const float* __restrict__ h,
                       const float* __restrict__ att, float* __restrict__ aq, float* __restrict__ ah){
  int v = blockIdx.x, t = threadIdx.x;
  float a1 = xq[(size_t)v*HH+t]*att[t];
  float a2 = h[(size_t)v*HH+t]*att[HH+t];
  #pragma unroll
  for (int off=32; off; off>>=1){ a1 += __shfl_down(a1,off); a2 += __shfl_down(a2,off); }
  __shared__ float s1[2], s2[2];
  if ((t&63)==0){ s1[t>>6]=a1; s2[t>>6]=a2; }
  __syncthreads();
  if (t==0){ aq[v]=s1[0]+s1[1]; ah[v]=s2[0]+s2[1]; }
}

// ---------- per-dst softmax -> alpha[e] ----------
__global__ void k_alpha(const int* __restrict__ edges, const int* __restrict__ drowptr,
                        const int* __restrict__ delist, const float* __restrict__ aq,
                        const float* __restrict__ ah, float* __restrict__ alpha){
  int v = blockIdx.x*blockDim.x + threadIdx.x;
  if (v >= NN) return;
  int beg = drowptr[v], end = drowptr[v+1];
  float aqv = aq[v], m = -3.4e38f;
  for (int i=beg;i<end;++i){
    int e = delist[i];
    float s = aqv + ah[esrc(edges,e)];
    s = s > 0.0f ? s : 0.2f*s;   // leaky_relu 0.2
    alpha[e] = s;
    m = fmaxf(m, s);
  }
  float den = 0.0f;
  for (int i=beg;i<end;++i){
    int e = delist[i];
    float t = expf(alpha[e]-m);
    alpha[e] = t; den += t;
  }
  float inv = 1.0f/den;
  for (int i=beg;i<end;++i) alpha[delist[i]] *= inv;
}

// ---------- cx[v] = sum_in alpha[e]*h[src] ----------
__global__ void k_cx(const float* __restrict__ h, const int* __restrict__ edges,
    const int* __restrict__ drowptr, const int* __restrict__ delist,
    const float* __restrict__ alpha, float* __restrict__ cx){
  int v = blockIdx.x, f = threadIdx.x;
  int beg = drowptr[v], end = drowptr[v+1];
  float acc = 0.0f;
  for (int i=beg;i<end;++i){
    int e = delist[i]; int u = esrc(edges,e);
    acc += alpha[e]*h[(size_t)u*HH+f];
  }
  cx[(size_t)v*HH+f] = acc;
}

// ---------- LEConv dots ----------
__global__ void k_le(const float* __restrict__ cx, const float* __restrict__ lw1,
                     const float* __restrict__ lw2, const float* __restrict__ lw3,
                     float* __restrict__ l1, float* __restrict__ l2, float* __restrict__ l3){
  int v = blockIdx.x, t = threadIdx.x;
  float cv = cx[(size_t)v*HH+t];
  float a = cv*lw1[t], b = cv*lw2[t], c = cv*lw3[t];
  #pragma unroll
  for (int off=32; off; off>>=1){ a += __shfl_down(a,off); b += __shfl_down(b,off); c += __shfl_down(c,off); }
  __shared__ float sa[2], sb[2], sc[2];
  if ((t&63)==0){ sa[t>>6]=a; sb[t>>6]=b; sc[t>>6]=c; }
  __syncthreads();
  if (t==0){ l1[v]=sa[0]+sa[1]; l2[v]=sb[0]+sb[1]; l3[v]=sc[0]+sc[1]; }
}

__global__ void k_fit(const int* __restrict__ edges, const int* __restrict__ drowptr,
                      const int* __restrict__ delist, const float* __restrict__ l1,
                      const float* __restrict__ l2, const float* __restrict__ l3,
                      const float* __restrict__ lb1, float* __restrict__ fit){
  int v = blockIdx.x*blockDim.x + threadIdx.x;
  if (v >= NN) return;
  int beg = drowptr[v], end = drowptr[v+1];
  float s = 0.0f;
  for (int i=beg;i<end;++i) s += l3[esrc(edges,delist[i])];
  float degf = (float)(end-beg);
  float x = l1[v] + lb1[0] + degf*l2[v] - s;
  fit[v] = 1.0f/(1.0f+expf(-x));
}

// ---------- top-K via single-block bitonic sort (set-exact; order irrelevant downstream) ----------
__global__ __launch_bounds__(1024) void k_topk(const float* __restrict__ fit, int* __restrict__ perm,
                        float* __restrict__ fitk, int* __restrict__ inv){
  __shared__ unsigned long long keys[NN];
  int tid = threadIdx.x;
  for (int i=tid;i<NN;i+=1024){
    unsigned u = __float_as_uint(fit[i]);
    unsigned mono = (u>>31) ? ~u : (u|0x80000000u);  // ascending-monotone map
    keys[i] = ((unsigned long long)(~mono)<<32) | (unsigned)i; // sort asc -> fit desc, idx asc
    inv[i] = -1;
  }
  __syncthreads();
  for (int k=2;k<=NN;k<<=1)
    for (int j=k>>1;j>0;j>>=1){
      for (int t=tid;t<NN;t+=1024){
        int ixj = t^j;
        if (ixj > t){
          bool up = ((t&k)==0);
          unsigned long long a = keys[t], b = keys[ixj];
          if (up ? (a>b) : (a<b)){ keys[t]=b; keys[ixj]=a; }
        }
      }
      __syncthreads();
    }
  for (int i=tid;i<KK;i+=1024){
    int idx = (int)(keys[i] & 0xffffffffu);
    perm[i]=idx; fitk[i]=fit[idx]; inv[idx]=i;
  }
}

__global__ void k_xp(const float* __restrict__ cx, const int* __restrict__ perm,
                     const float* __restrict__ fitk, float* __restrict__ xp){
  int j = blockIdx.x, f = threadIdx.x;
  xp[(size_t)j*HH+f] = cx[(size_t)perm[j]*HH+f]*fitk[j];
}

// ---------- S (CSR by src): entries (col=inv[dst], val=alpha) ----------
__global__ void k_scnt(const int* __restrict__ edges, const int* __restrict__ inv, int* __restrict__ scnt){
  int e = blockIdx.x*blockDim.x + threadIdx.x;
  if (e < ELn && inv[edst(edges,e)] >= 0) atomicAdd(&scnt[esrc(edges,e)],1);
}

__global__ void k_fill_s(const int* __restrict__ edges, const int* __restrict__ inv,
                         const float* __restrict__ alpha, int* __restrict__ scur, int2* __restrict__ spair){
  int e = blockIdx.x*blockDim.x + threadIdx.x;
  if (e < ELn){
    int j = inv[edst(edges,e)];
    if (j >= 0){
      int pos = atomicAdd(&scur[esrc(edges,e)],1);
      spair[pos] = make_int2(j, __float_as_int(alpha[e]));
    }
  }
}

// ---------- x_out = S @ xp ----------
__global__ void k_xout(const float* __restrict__ xp, const int* __restrict__ srowptr,
                       const int2* __restrict__ spair, float* __restrict__ xout){
  int u = blockIdx.x, f = threadIdx.x;
  int beg = srowptr[u], end = srowptr[u+1];
  float acc = 0.0f;
  for (int i=beg;i<end;++i){
    int2 p = spair[i];
    acc += __int_as_float(p.y)*xp[(size_t)p.x*HH+f];
  }
  xout[(size_t)u*HH+f] = acc;
}

// ---------- Ac = S^T A S via per-edge row-pair outer products (atomics) ----------
__global__ void k_ac(const int* __restrict__ edges, const int* __restrict__ srowptr,
                     const int2* __restrict__ spair, float* __restrict__ Ac){
  int e = blockIdx.x*blockDim.x + threadIdx.x;
  if (e >= ELn) return;
  int u = esrc(edges,e), v = edst(edges,e);
  int ub = srowptr[u], ue = srowptr[u+1];
  int vb = srowptr[v], ve = srowptr[v+1];
  for (int i=ub;i<ue;++i){
    int2 pu = spair[i];
    float a = __int_as_float(pu.y);
    float* acrow = Ac + (size_t)pu.x*KK;
    for (int j=vb;j<ve;++j){
      int2 pv = spair[j];
      atomicAdd(&acrow[pv.x], a*__int_as_float(pv.y));
    }
  }
}

// ---------- adj_out = S Ac S^T, fused: block handles 4 rows u; U rows in LDS ----------
__global__ __launch_bounds__(256) void k_adj(const float* __restrict__ Ac, const int* __restrict__ srowptr,
                       const int2* __restrict__ spair, float* __restrict__ adj){
  __shared__ float Uf[4*KK];  // 64KB: U[g][q] = sum_p S[u0+g,p]*Ac[p,q]
  int tid = threadIdx.x;
  int u0 = blockIdx.x*4;
  for (int i=tid;i<4*KK;i+=256) Uf[i]=0.0f;
  __syncthreads();
  for (int g=0; g<4; ++g){
    int beg = srowptr[u0+g], end = srowptr[u0+g+1];
    float* Ug = &Uf[g*KK];
    for (int i=beg;i<end;++i){
      int2 pr = spair[i];              // broadcast load
      float a = __int_as_float(pr.y);
      const float* acrow = Ac + (size_t)pr.x*KK;
      for (int q=tid;q<KK;q+=256) Ug[q] += a*acrow[q];
    }
  }
  __syncthreads();
  float* out0 = adj + (size_t)u0*NN;
  for (int wb=0; wb<NN; wb+=256){
    int w = wb + tid;
    int beg = srowptr[w], end = srowptr[w+1];
    float a0=0,a1=0,a2=0,a3=0;
    for (int i=beg;i<end;++i){
      int2 p = spair[i];
      float b = __int_as_float(p.y);
      int q = p.x;
      a0 += b*Uf[q];
      a1 += b*Uf[KK+q];
      a2 += b*Uf[2*KK+q];
      a3 += b*Uf[3*KK+q];
    }
    out0[w]=a0; out0[NN+w]=a1; out0[2*(size_t)NN+w]=a2; out0[3*(size_t)NN+w]=a3;
  }
}

extern "C" void kernel_launch(void* const* d_in, const int* in_sizes, int n_in,
                              void* d_out, int out_size, void* d_ws, size_t ws_size,
                              hipStream_t stream){
  const float* nodes = (const float*)d_in[0];
  const int*   edges = (const int*)d_in[1];
  // d_in[2] = batch (unused, all zeros)
  const float* w1=(const float*)d_in[3];  const float* b1=(const float*)d_in[4];
  const float* w2=(const float*)d_in[5];  const float* b2=(const float*)d_in[6];
  const float* w3=(const float*)d_in[7];  const float* b3=(const float*)d_in[8];
  const float* w4=(const float*)d_in[9];  const float* b4=(const float*)d_in[10];
  const float* w5=(const float*)d_in[11]; const float* b5=(const float*)d_in[12];
  const float* wq=(const float*)d_in[13]; const float* bq=(const float*)d_in[14];
  const float* att=(const float*)d_in[15];
  const float* lw1=(const float*)d_in[16]; const float* lb1=(const float*)d_in[17];
  const float* lw2=(const float*)d_in[18]; const float* lw3=(const float*)d_in[19];

  // ---- workspace layout (d_ws): ~70MB ----
  char* ws = (char*)d_ws;
  size_t off = 0;
  auto take = [&](size_t bytes)->char*{
    char* p = ws + off;
    off = (off + bytes + 255) & ~(size_t)255;
    return p;
  };
  int*   deg     = (int*)  take((size_t)NN*4);
  float* dis     = (float*)take((size_t)NN*4);
  int*   drowptr = (int*)  take((size_t)(NN+1)*4);
  int*   dcur    = (int*)  take((size_t)NN*4);
  int*   delist  = (int*)  take((size_t)ELn*4);
  float* alpha   = (float*)take((size_t)ELn*4);
  float* aq      = (float*)take((size_t)NN*4);
  float* ah      = (float*)take((size_t)NN*4);
  float* l1      = (float*)take((size_t)NN*4);
  float* l2      = (float*)take((size_t)NN*4);
  float* l3      = (float*)take((size_t)NN*4);
  float* fit     = (float*)take((size_t)NN*4);
  int*   perm    = (int*)  take((size_t)KK*4);
  float* fitk    = (float*)take((size_t)KK*4);
  int*   inv     = (int*)  take((size_t)NN*4);
  int*   scnt    = (int*)  take((size_t)NN*4);
  int*   srowptr = (int*)  take((size_t)(NN+1)*4);
  int*   scur    = (int*)  take((size_t)NN*4);
  int2*  spair   = (int2*) take((size_t)ELn*8);
  float* Ac      = (float*)take((size_t)KK*KK*4);
  (void)ws_size; (void)in_sizes; (void)n_in; (void)out_size;

  // ---- big node buffers live in d_out's adj region (overwritten last by k_adj) ----
  float* out_x2 = (float*)d_out;                       // [NN,HH]
  float* adj    = (float*)d_out + (size_t)NN*HH;       // [NN,NN]
  float* BA = adj + 0*(size_t)NN*HH;  // y (gemm out)
  float* BB = adj + 1*(size_t)NN*HH;  // h1 / h3
  float* BC = adj + 2*(size_t)NN*HH;  // h (post GCN2)
  float* BD = adj + 3*(size_t)NN*HH;  // xq_pre / h4
  float* BE = adj + 4*(size_t)NN*HH;  // xq
  float* BF = adj + 5*(size_t)NN*HH;  // cx
  float* BG = adj + 6*(size_t)NN*HH;  // x_out
  float* xp = adj + 7*(size_t)NN*HH;  // [KK,HH]

  const int EB = ELn/256;  // 544 exact

  // degree + CSR-by-dst
  hipMemsetAsync(deg, 0, (size_t)NN*4, stream);
  k_count_indeg<<<EB,256,0,stream>>>(edges,deg);
  k_dis<<<NN/256,256,0,stream>>>(deg,dis);
  k_scan<<<1,1024,0,stream>>>(deg,drowptr,dcur);
  k_fill_dst<<<EB,256,0,stream>>>(edges,dcur,delist);

  // GCN1, GCN2
  k_gemm128<<<NN/32,256,0,stream>>>(nodes,w1,nullptr,BA);
  k_gcn_scatter<1><<<NN,128,0,stream>>>(BA,edges,drowptr,delist,dis,b1,BB);
  k_gemm128<<<NN/32,256,0,stream>>>(BB,w2,nullptr,BA);
  k_gcn_scatter<1><<<NN,128,0,stream>>>(BA,edges,drowptr,delist,dis,b2,BC);

  // ASAP pooling
  k_segmax<<<NN,128,0,stream>>>(BC,edges,drowptr,delist,BD);
  k_gemm128<<<NN/32,256,0,stream>>>(BD,wq,bq,BE);
  k_aqah<<<NN,128,0,stream>>>(BE,BC,att,aq,ah);
  k_alpha<<<NN/256,256,0,stream>>>(edges,drowptr,delist,aq,ah,alpha);
  k_cx<<<NN,128,0,stream>>>(BC,edges,drowptr,delist,alpha,BF);
  k_le<<<NN,128,0,stream>>>(BF,lw1,lw2,lw3,l1,l2,l3);
  k_fit<<<NN/256,256,0,stream>>>(edges,drowptr,delist,l1,l2,l3,lb1,fit);
  k_topk<<<1,1024,0,stream>>>(fit,perm,fitk,inv);
  k_xp<<<KK,128,0,stream>>>(BF,perm,fitk,xp);

  // S CSR (by src)
  hipMemsetAsync(scnt, 0, (size_t)NN*4, stream);
  k_scnt<<<EB,256,0,stream>>>(edges,inv,scnt);
  k_scan<<<1,1024,0,stream>>>(scnt,srowptr,scur);
  k_fill_s<<<EB,256,0,stream>>>(edges,inv,alpha,scur,spair);

  // x_out = S @ xp, then GCN3/4/5 -> x2 (first chunk of d_out)
  k_xout<<<NN,128,0,stream>>>(xp,srowptr,spair,BG);
  k_gemm128<<<NN/32,256,0,stream>>>(BG,w3,nullptr,BA);
  k_gcn_scatter<1><<<NN,128,0,stream>>>(BA,edges,drowptr,delist,dis,b3,BB);
  k_gemm128<<<NN/32,256,0,stream>>>(BB,w4,nullptr,BA);
  k_gcn_scatter<1><<<NN,128,0,stream>>>(BA,edges,drowptr,delist,dis,b4,BD);
  k_gemm128<<<NN/32,256,0,stream>>>(BD,w5,nullptr,BA);
  k_gcn_scatter<0><<<NN,128,0,stream>>>(BA,edges,drowptr,delist,dis,b5,out_x2);

  // Ac = S^T A S, then adj_out = S Ac S^T (overwrites scratch region last)
  hipMemsetAsync(Ac, 0, (size_t)KK*KK*4, stream);
  k_ac<<<EB,256,0,stream>>>(edges,srowptr,spair,Ac);
  k_adj<<<NN/4,256,0,stream>>>(Ac,srowptr,spair,adj);
}

// Round 2
// 1208.580 us; speedup vs baseline: 1.8873x; 1.8873x over previous
//
#include <hip/hip_runtime.h>
#include <math.h>

#define NN 8192
#define EE 131072
#define ELn 139264   // EE + NN (edges + self loops)
#define HH 128
#define KK 4096

__device__ __forceinline__ int esrc(const int* __restrict__ edges, int e){ return e < EE ? edges[e] : e - EE; }
__device__ __forceinline__ int edst(const int* __restrict__ edges, int e){ return e < EE ? edges[EE + e] : e - EE; }

// ---------- degree counts ----------
__global__ void k_count_indeg(const int* __restrict__ edges, int* __restrict__ deg){
  int e = blockIdx.x*blockDim.x + threadIdx.x;
  if (e < ELn) atomicAdd(&deg[edst(edges,e)], 1);
}
__global__ void k_count_src(const int* __restrict__ edges, int* __restrict__ cnt){
  int e = blockIdx.x*blockDim.x + threadIdx.x;
  if (e < ELn) atomicAdd(&cnt[esrc(edges,e)], 1);
}

__global__ void k_dis(const int* __restrict__ deg, float* __restrict__ dis){
  int v = blockIdx.x*blockDim.x + threadIdx.x;
  if (v < NN){ float d = (float)deg[v]; d = d < 1.0f ? 1.0f : d; dis[v] = 1.0f/sqrtf(d); }
}

// single-block exclusive scan over 1024*IPT counts -> rowptr, cursor copy
template<int IPT>
__global__ __launch_bounds__(1024) void k_scan(const int* __restrict__ cnt, int* __restrict__ rowptr, int* __restrict__ cur){
  __shared__ int part[1024];
  int tid = threadIdx.x;
  int base = tid*IPT;
  int loc[IPT]; int s=0;
  #pragma unroll
  for (int i=0;i<IPT;i++) loc[i]=cnt[base+i];
  #pragma unroll
  for (int i=0;i<IPT;i++){ int t=loc[i]; loc[i]=s; s+=t; }
  part[tid]=s;
  __syncthreads();
  for (int off=1; off<1024; off<<=1){
    int v = (tid>=off)? part[tid-off] : 0;
    __syncthreads();
    part[tid]+=v;
    __syncthreads();
  }
  int cb = part[tid]-s;
  #pragma unroll
  for (int i=0;i<IPT;i++){ int r=cb+loc[i]; rowptr[base+i]=r; cur[base+i]=r; }
  if (tid==1023) rowptr[1024*IPT]=part[1023];
}

__global__ void k_fill_dst(const int* __restrict__ edges, int* __restrict__ cur,
                           int* __restrict__ delist, int* __restrict__ desrc){
  int e = blockIdx.x*blockDim.x + threadIdx.x;
  if (e < ELn){
    int v = edst(edges,e);
    int pos = atomicAdd(&cur[v],1);
    delist[pos] = e;
    desrc[pos]  = esrc(edges,e);
  }
}
__global__ void k_fill_src(const int* __restrict__ edges, int* __restrict__ cur, int* __restrict__ esdst){
  int e = blockIdx.x*blockDim.x + threadIdx.x;
  if (e < ELn){
    int u = esrc(edges,e);
    int pos = atomicAdd(&cur[u],1);
    esdst[pos] = edst(edges,e);
  }
}

// ---------- fp32 GEMM: y[r,c] = (x@W + bias?) * scale[r]? ; 8 rows/block ----------
__global__ __launch_bounds__(256) void k_gemm8(const float* __restrict__ x, const float* __restrict__ W,
     const float* __restrict__ bias, const float* __restrict__ scale, float* __restrict__ y){
  __shared__ float xl[8*HH];
  int tid = threadIdx.x;
  int r0 = blockIdx.x*8;
  {
    int row = tid>>5, col = (tid&31)*4;
    *(float4*)&xl[row*HH+col] = *(const float4*)&x[(size_t)(r0+row)*HH+col];
  }
  __syncthreads();
  int c = tid & 127, h = tid>>7;
  float acc0=0,acc1=0,acc2=0,acc3=0;
  const float* xr = &xl[h*4*HH];
  #pragma unroll 8
  for (int k=0;k<HH;++k){
    float wv = W[k*HH+c];
    acc0 += xr[k]*wv;
    acc1 += xr[HH+k]*wv;
    acc2 += xr[2*HH+k]*wv;
    acc3 += xr[3*HH+k]*wv;
  }
  float b = bias ? bias[c] : 0.0f;
  float r[4] = {acc0+b, acc1+b, acc2+b, acc3+b};
  #pragma unroll
  for (int j=0;j<4;j++){
    int rr = r0 + h*4 + j;
    float v = r[j];
    if (scale) v *= scale[rr];
    y[(size_t)rr*HH + c] = v;
  }
}

// ---------- GCN scatter: out[v] = (tanh?)(bias + dis[v]*sum_in y'[src]) (y' prescaled by dis[src]) ----------
template<int TANH>
__global__ void k_gcn(const float* __restrict__ y, const int* __restrict__ desrc,
    const int* __restrict__ drowptr, const float* __restrict__ dis,
    const float* __restrict__ bias, float* __restrict__ out){
  int v = blockIdx.x, f = threadIdx.x;
  int beg = drowptr[v], end = drowptr[v+1];
  float acc = 0.0f;
  for (int i=beg;i<end;++i){
    int u = desrc[i];
    acc += y[(size_t)u*HH+f];
  }
  acc = acc*dis[v] + bias[f];
  if (TANH) acc = tanhf(acc);
  out[(size_t)v*HH+f] = acc;
}

// ---------- segment max over in-edges ----------
__global__ void k_segmax(const float* __restrict__ h, const int* __restrict__ desrc,
    const int* __restrict__ drowptr, float* __restrict__ out){
  int v = blockIdx.x, f = threadIdx.x;
  int beg = drowptr[v], end = drowptr[v+1];
  float m = -3.4e38f;
  for (int i=beg;i<end;++i){
    int u = desrc[i];
    m = fmaxf(m, h[(size_t)u*HH+f]);
  }
  out[(size_t)v*HH+f] = m;
}

// ---------- attention dots ----------
__global__ void k_aqah(const float* __restrict__ xq, const float* __restrict__ h,
                       const float* __restrict__ att, float* __restrict__ aq, float* __restrict__ ah){
  int v = blockIdx.x, t = threadIdx.x;
  float a1 = xq[(size_t)v*HH+t]*att[t];
  float a2 = h[(size_t)v*HH+t]*att[HH+t];
  #pragma unroll
  for (int off=32; off; off>>=1){ a1 += __shfl_down(a1,off); a2 += __shfl_down(a2,off); }
  __shared__ float s1[2], s2[2];
  if ((t&63)==0){ s1[t>>6]=a1; s2[t>>6]=a2; }
  __syncthreads();
  if (t==0){ aq[v]=s1[0]+s1[1]; ah[v]=s2[0]+s2[1]; }
}

// ---------- per-dst softmax -> alpha[e] (wave per node) ----------
__global__ __launch_bounds__(256) void k_alpha(const int* __restrict__ delist, const int* __restrict__ desrc,
    const int* __restrict__ drowptr, const float* __restrict__ aq, const float* __restrict__ ah,
    float* __restrict__ alpha){
  int v = blockIdx.x*4 + (threadIdx.x>>6);
  int lane = threadIdx.x & 63;
  int beg = drowptr[v], end = drowptr[v+1];
  float aqv = aq[v];
  float m = -3.4e38f;
  for (int i=beg+lane; i<end; i+=64){
    float s = aqv + ah[desrc[i]];
    s = s > 0.0f ? s : 0.2f*s;
    m = fmaxf(m, s);
  }
  #pragma unroll
  for (int off=32; off; off>>=1) m = fmaxf(m, __shfl_xor(m, off));
  float den = 0.0f;
  for (int i=beg+lane; i<end; i+=64){
    float s = aqv + ah[desrc[i]];
    s = s > 0.0f ? s : 0.2f*s;
    den += expf(s - m);
  }
  #pragma unroll
  for (int off=32; off; off>>=1) den += __shfl_xor(den, off);
  float inv = 1.0f/den;
  for (int i=beg+lane; i<end; i+=64){
    float s = aqv + ah[desrc[i]];
    s = s > 0.0f ? s : 0.2f*s;
    alpha[delist[i]] = expf(s - m)*inv;
  }
}

// ---------- cx[v] = sum_in alpha[e]*h[src] ----------
__global__ void k_cx(const float* __restrict__ h, const int* __restrict__ delist,
    const int* __restrict__ desrc, const int* __restrict__ drowptr,
    const float* __restrict__ alpha, float* __restrict__ cx){
  int v = blockIdx.x, f = threadIdx.x;
  int beg = drowptr[v], end = drowptr[v+1];
  float acc = 0.0f;
  for (int i=beg;i<end;++i){
    acc += alpha[delist[i]]*h[(size_t)desrc[i]*HH+f];
  }
  cx[(size_t)v*HH+f] = acc;
}

// ---------- LEConv dots ----------
__global__ void k_le(const float* __restrict__ cx, const float* __restrict__ lw1,
                     const float* __restrict__ lw2, const float* __restrict__ lw3,
                     float* __restrict__ l1, float* __restrict__ l2, float* __restrict__ l3){
  int v = blockIdx.x, t = threadIdx.x;
  float cv = cx[(size_t)v*HH+t];
  float a = cv*lw1[t], b = cv*lw2[t], c = cv*lw3[t];
  #pragma unroll
  for (int off=32; off; off>>=1){ a += __shfl_down(a,off); b += __shfl_down(b,off); c += __shfl_down(c,off); }
  __shared__ float sa[2], sb[2], sc[2];
  if ((t&63)==0){ sa[t>>6]=a; sb[t>>6]=b; sc[t>>6]=c; }
  __syncthreads();
  if (t==0){ l1[v]=sa[0]+sa[1]; l2[v]=sb[0]+sb[1]; l3[v]=sc[0]+sc[1]; }
}

__global__ __launch_bounds__(256) void k_fit(const int* __restrict__ desrc, const int* __restrict__ drowptr,
    const float* __restrict__ l1, const float* __restrict__ l2, const float* __restrict__ l3,
    const float* __restrict__ lb1, float* __restrict__ fit){
  int v = blockIdx.x*4 + (threadIdx.x>>6);
  int lane = threadIdx.x & 63;
  int beg = drowptr[v], end = drowptr[v+1];
  float s = 0.0f;
  for (int i=beg+lane;i<end;i+=64) s += l3[desrc[i]];
  #pragma unroll
  for (int off=32; off; off>>=1) s += __shfl_xor(s, off);
  if (lane==0){
    float degf = (float)(end-beg);
    float x = l1[v] + lb1[0] + degf*l2[v] - s;
    fit[v] = 1.0f/(1.0f+expf(-x));
  }
}

// ---------- top-K via single-block bitonic sort (set-exact; order irrelevant downstream) ----------
__global__ __launch_bounds__(1024) void k_topk(const float* __restrict__ fit, int* __restrict__ perm,
                        float* __restrict__ fitk, int* __restrict__ inv){
  __shared__ unsigned long long keys[NN];
  int tid = threadIdx.x;
  for (int i=tid;i<NN;i+=1024){
    unsigned u = __float_as_uint(fit[i]);
    unsigned mono = (u>>31) ? ~u : (u|0x80000000u);
    keys[i] = ((unsigned long long)(~mono)<<32) | (unsigned)i;
    inv[i] = -1;
  }
  __syncthreads();
  for (int k=2;k<=NN;k<<=1)
    for (int j=k>>1;j>0;j>>=1){
      for (int t=tid;t<NN;t+=1024){
        int ixj = t^j;
        if (ixj > t){
          bool up = ((t&k)==0);
          unsigned long long a = keys[t], b = keys[ixj];
          if (up ? (a>b) : (a<b)){ keys[t]=b; keys[ixj]=a; }
        }
      }
      __syncthreads();
    }
  for (int i=tid;i<KK;i+=1024){
    int idx = (int)(keys[i] & 0xffffffffu);
    perm[i]=idx; fitk[i]=fit[idx]; inv[idx]=i;
  }
}

__global__ void k_xp(const float* __restrict__ cx, const int* __restrict__ perm,
                     const float* __restrict__ fitk, float* __restrict__ xp){
  int j = blockIdx.x, f = threadIdx.x;
  xp[(size_t)j*HH+f] = cx[(size_t)perm[j]*HH+f]*fitk[j];
}

// ---------- S (CSR by src) ----------
__global__ void k_scnt(const int* __restrict__ edges, const int* __restrict__ inv, int* __restrict__ scnt){
  int e = blockIdx.x*blockDim.x + threadIdx.x;
  if (e < ELn && inv[edst(edges,e)] >= 0) atomicAdd(&scnt[esrc(edges,e)],1);
}

__global__ void k_fill_s(const int* __restrict__ edges, const int* __restrict__ inv,
                         const float* __restrict__ alpha, int* __restrict__ scur,
                         int2* __restrict__ spair, int* __restrict__ srow_of){
  int e = blockIdx.x*blockDim.x + threadIdx.x;
  if (e < ELn){
    int j = inv[edst(edges,e)];
    if (j >= 0){
      int u = esrc(edges,e);
      int pos = atomicAdd(&scur[u],1);
      spair[pos] = make_int2(j, __float_as_int(alpha[e]));
      srow_of[pos] = u;
    }
  }
}

// ---------- CSC of S by column ----------
__global__ void k_col_cnt(const int2* __restrict__ spair, const int* __restrict__ srowptr, int* __restrict__ ccnt){
  int i = blockIdx.x*blockDim.x + threadIdx.x;
  if (i < srowptr[NN]) atomicAdd(&ccnt[spair[i].x], 1);
}
__global__ void k_col_fill(const int2* __restrict__ spair, const int* __restrict__ srow_of,
                           const int* __restrict__ srowptr, int* __restrict__ ccur,
                           int* __restrict__ colu, float* __restrict__ cval){
  int i = blockIdx.x*blockDim.x + threadIdx.x;
  if (i < srowptr[NN]){
    int2 p = spair[i];
    int pos = atomicAdd(&ccur[p.x], 1);
    colu[pos] = srow_of[i];
    cval[pos] = __int_as_float(p.y);
  }
}

// ---------- x_out = S @ xp ----------
__global__ void k_xout(const float* __restrict__ xp, const int* __restrict__ srowptr,
                       const int2* __restrict__ spair, float* __restrict__ xout){
  int u = blockIdx.x, f = threadIdx.x;
  int beg = srowptr[u], end = srowptr[u+1];
  float acc = 0.0f;
  for (int i=beg;i<end;++i){
    int2 p = spair[i];
    acc += __int_as_float(p.y)*xp[(size_t)p.x*HH+f];
  }
  xout[(size_t)u*HH+f] = acc;
}

// ---------- Ac row p = sum_{(u,val) in col p of S} val * sum_{v in outN(u)} S[v,:] ----------
#define ACCAP 2048
__global__ __launch_bounds__(256) void k_ac2(const int* __restrict__ cptr, const int* __restrict__ colu,
     const float* __restrict__ cval, const int* __restrict__ esptr, const int* __restrict__ esdst,
     const int* __restrict__ srowptr, const int2* __restrict__ spair, float* __restrict__ Ac){
  __shared__ float row[KK];
  __shared__ int   lv[ACCAP];
  __shared__ float lval[ACCAP];
  int tid = threadIdx.x;
  int p = blockIdx.x;
  for (int i=tid;i<KK;i+=256) row[i]=0.0f;
  int cb = cptr[p], ce = cptr[p+1];
  int base = 0;
  int j = cb;
  while (true){
    // stage (v, val) pairs while they fit
    while (j < ce){
      int u = colu[j]; float val = cval[j];
      int eb = esptr[u], d = esptr[u+1]-eb;
      if (base + d > ACCAP) break;
      for (int t=tid; t<d; t+=256){ lv[base+t]=esdst[eb+t]; lval[base+t]=val; }
      base += d; ++j;
    }
    __syncthreads();
    for (int i=tid;i<base;i+=256){
      int v = lv[i]; float a = lval[i];
      int sb = srowptr[v], se = srowptr[v+1];
      for (int k=sb;k<se;++k){
        int2 q = spair[k];
        atomicAdd(&row[q.x], a*__int_as_float(q.y));
      }
    }
    __syncthreads();
    base = 0;
    if (j >= ce) break;
  }
  for (int i=tid;i<KK;i+=256) Ac[(size_t)p*KK+i] = row[i];
}

// ---------- adj_out = S Ac S^T, fused; 4 rows/block, 1024 threads, U in LDS [q][4] ----------
__global__ __launch_bounds__(1024) void k_adj(const float* __restrict__ Ac, const int* __restrict__ srowptr,
      const int2* __restrict__ spair, float* __restrict__ adj){
  __shared__ float Uf[KK*4];  // 64 KB, layout [q][g]
  int tid = threadIdx.x;
  int u0 = blockIdx.x*4;
  float acc[4][4];
  #pragma unroll
  for (int jj=0;jj<4;jj++)
    #pragma unroll
    for (int g=0;g<4;g++) acc[jj][g]=0.f;
  int q0 = tid*4;
  // phase 1: build 4 rows of U = S[u0..u0+3,:] @ Ac in registers (q-slice per thread)
  #pragma unroll
  for (int g=0; g<4; ++g){
    int beg = srowptr[u0+g], end = srowptr[u0+g+1];
    for (int i=beg;i<end;++i){
      int2 pr = spair[i];
      float a = __int_as_float(pr.y);
      float4 av = *(const float4*)(Ac + (size_t)pr.x*KK + q0);
      acc[0][g] += a*av.x; acc[1][g] += a*av.y; acc[2][g] += a*av.z; acc[3][g] += a*av.w;
    }
  }
  #pragma unroll
  for (int jj=0;jj<4;jj++){
    *(float4*)&Uf[(q0+jj)*4] = make_float4(acc[jj][0],acc[jj][1],acc[jj][2],acc[jj][3]);
  }
  __syncthreads();
  // phase 2: adj[u0+g][w] = sum_q S[w,q] * U[g][q] ; one ds_read_b128 per S-entry
  for (int wb=0; wb<NN; wb+=1024){
    int w = wb + tid;
    int beg = srowptr[w], end = srowptr[w+1];
    float r0=0,r1=0,r2=0,r3=0;
    for (int i=beg;i<end;++i){
      int2 p = spair[i];
      float b = __int_as_float(p.y);
      float4 u4 = *(const float4*)&Uf[p.x*4];
      r0 += b*u4.x; r1 += b*u4.y; r2 += b*u4.z; r3 += b*u4.w;
    }
    adj[(size_t)(u0+0)*NN + w] = r0;
    adj[(size_t)(u0+1)*NN + w] = r1;
    adj[(size_t)(u0+2)*NN + w] = r2;
    adj[(size_t)(u0+3)*NN + w] = r3;
  }
}

extern "C" void kernel_launch(void* const* d_in, const int* in_sizes, int n_in,
                              void* d_out, int out_size, void* d_ws, size_t ws_size,
                              hipStream_t stream){
  const float* nodes = (const float*)d_in[0];
  const int*   edges = (const int*)d_in[1];
  const float* w1=(const float*)d_in[3];  const float* b1=(const float*)d_in[4];
  const float* w2=(const float*)d_in[5];  const float* b2=(const float*)d_in[6];
  const float* w3=(const float*)d_in[7];  const float* b3=(const float*)d_in[8];
  const float* w4=(const float*)d_in[9];  const float* b4=(const float*)d_in[10];
  const float* w5=(const float*)d_in[11]; const float* b5=(const float*)d_in[12];
  const float* wq=(const float*)d_in[13]; const float* bq=(const float*)d_in[14];
  const float* att=(const float*)d_in[15];
  const float* lw1=(const float*)d_in[16]; const float* lb1=(const float*)d_in[17];
  const float* lw2=(const float*)d_in[18]; const float* lw3=(const float*)d_in[19];

  // ---- workspace layout (d_ws) ----
  char* ws = (char*)d_ws;
  size_t off = 0;
  auto take = [&](size_t bytes)->char*{
    char* p = ws + off;
    off = (off + bytes + 255) & ~(size_t)255;
    return p;
  };
  int*   deg     = (int*)  take((size_t)NN*4);
  float* dis     = (float*)take((size_t)NN*4);
  int*   drowptr = (int*)  take((size_t)(NN+1)*4);
  int*   dcur    = (int*)  take((size_t)NN*4);
  int*   delist  = (int*)  take((size_t)ELn*4);
  float* alpha   = (float*)take((size_t)ELn*4);
  float* aq      = (float*)take((size_t)NN*4);
  float* ah      = (float*)take((size_t)NN*4);
  float* l1      = (float*)take((size_t)NN*4);
  float* l2      = (float*)take((size_t)NN*4);
  float* l3      = (float*)take((size_t)NN*4);
  float* fit     = (float*)take((size_t)NN*4);
  int*   perm    = (int*)  take((size_t)KK*4);
  float* fitk    = (float*)take((size_t)KK*4);
  int*   inv     = (int*)  take((size_t)NN*4);
  int*   scnt    = (int*)  take((size_t)NN*4);
  int*   srowptr = (int*)  take((size_t)(NN+1)*4);
  int*   scur    = (int*)  take((size_t)NN*4);
  int2*  spair   = (int2*) take((size_t)ELn*8);
  int*   ecnt    = (int*)  take((size_t)NN*4);
  int*   esptr   = (int*)  take((size_t)(NN+1)*4);
  int*   ecur    = (int*)  take((size_t)NN*4);
  int*   ccnt    = (int*)  take((size_t)KK*4);
  int*   cptr    = (int*)  take((size_t)(KK+1)*4);
  int*   ccur    = (int*)  take((size_t)KK*4);
  float* Ac      = (float*)take((size_t)KK*KK*4);
  (void)ws_size; (void)in_sizes; (void)n_in; (void)out_size;

  // ---- big node buffers live in d_out's adj region (overwritten last by k_adj) ----
  float* out_x2 = (float*)d_out;                       // [NN,HH]
  float* adj    = (float*)d_out + (size_t)NN*HH;       // [NN,NN]
  float* BA = adj + 0*(size_t)NN*HH;  // gemm out
  float* BB = adj + 1*(size_t)NN*HH;  // h1 / h3
  float* BC = adj + 2*(size_t)NN*HH;  // h (post GCN2)
  float* BD = adj + 3*(size_t)NN*HH;  // segmax / h4
  float* BE = adj + 4*(size_t)NN*HH;  // xq
  float* BF = adj + 5*(size_t)NN*HH;  // cx
  float* BG = adj + 6*(size_t)NN*HH;  // x_out
  float* xp = adj + 7*(size_t)NN*HH;  // [KK,HH]
  // more scratch inside adj region (all dead before k_adj writes adj)
  char*  sc2 = (char*)(adj + 8*(size_t)NN*HH);
  int*   desrc   = (int*)  sc2;                       sc2 += (size_t)ELn*4;
  int*   esdst   = (int*)  sc2;                       sc2 += (size_t)ELn*4;
  int*   srow_of = (int*)  sc2;                       sc2 += (size_t)ELn*4;
  int*   colu    = (int*)  sc2;                       sc2 += (size_t)ELn*4;
  float* cval    = (float*)sc2;                       sc2 += (size_t)ELn*4;

  const int EB = ELn/256;  // 544 exact

  // degree + CSR-by-dst + CSR-by-src
  hipMemsetAsync(deg, 0, (size_t)NN*4, stream);
  hipMemsetAsync(ecnt, 0, (size_t)NN*4, stream);
  k_count_indeg<<<EB,256,0,stream>>>(edges,deg);
  k_count_src<<<EB,256,0,stream>>>(edges,ecnt);
  k_dis<<<NN/256,256,0,stream>>>(deg,dis);
  k_scan<8><<<1,1024,0,stream>>>(deg,drowptr,dcur);
  k_fill_dst<<<EB,256,0,stream>>>(edges,dcur,delist,desrc);
  k_scan<8><<<1,1024,0,stream>>>(ecnt,esptr,ecur);
  k_fill_src<<<EB,256,0,stream>>>(edges,ecur,esdst);

  // GCN1, GCN2 (gemm prescales rows by dis[src])
  k_gemm8<<<NN/8,256,0,stream>>>(nodes,w1,nullptr,dis,BA);
  k_gcn<1><<<NN,128,0,stream>>>(BA,desrc,drowptr,dis,b1,BB);
  k_gemm8<<<NN/8,256,0,stream>>>(BB,w2,nullptr,dis,BA);
  k_gcn<1><<<NN,128,0,stream>>>(BA,desrc,drowptr,dis,b2,BC);

  // ASAP pooling
  k_segmax<<<NN,128,0,stream>>>(BC,desrc,drowptr,BD);
  k_gemm8<<<NN/8,256,0,stream>>>(BD,wq,bq,nullptr,BE);
  k_aqah<<<NN,128,0,stream>>>(BE,BC,att,aq,ah);
  k_alpha<<<NN/4,256,0,stream>>>(delist,desrc,drowptr,aq,ah,alpha);
  k_cx<<<NN,128,0,stream>>>(BC,delist,desrc,drowptr,alpha,BF);
  k_le<<<NN,128,0,stream>>>(BF,lw1,lw2,lw3,l1,l2,l3);
  k_fit<<<NN/4,256,0,stream>>>(desrc,drowptr,l1,l2,l3,lb1,fit);
  k_topk<<<1,1024,0,stream>>>(fit,perm,fitk,inv);
  k_xp<<<KK,128,0,stream>>>(BF,perm,fitk,xp);

  // S CSR (by src) + CSC (by col)
  hipMemsetAsync(scnt, 0, (size_t)NN*4, stream);
  k_scnt<<<EB,256,0,stream>>>(edges,inv,scnt);
  k_scan<8><<<1,1024,0,stream>>>(scnt,srowptr,scur);
  k_fill_s<<<EB,256,0,stream>>>(edges,inv,alpha,scur,spair,srow_of);
  hipMemsetAsync(ccnt, 0, (size_t)KK*4, stream);
  k_col_cnt<<<EB,256,0,stream>>>(spair,srowptr,ccnt);
  k_scan<4><<<1,1024,0,stream>>>(ccnt,cptr,ccur);
  k_col_fill<<<EB,256,0,stream>>>(spair,srow_of,srowptr,ccur,colu,cval);

  // x_out = S @ xp, then GCN3/4/5 -> x2 (first chunk of d_out)
  k_xout<<<NN,128,0,stream>>>(xp,srowptr,spair,BG);
  k_gemm8<<<NN/8,256,0,stream>>>(BG,w3,nullptr,dis,BA);
  k_gcn<1><<<NN,128,0,stream>>>(BA,desrc,drowptr,dis,b3,BB);
  k_gemm8<<<NN/8,256,0,stream>>>(BB,w4,nullptr,dis,BA);
  k_gcn<1><<<NN,128,0,stream>>>(BA,desrc,drowptr,dis,b4,BD);
  k_gemm8<<<NN/8,256,0,stream>>>(BD,w5,nullptr,dis,BA);
  k_gcn<0><<<NN,128,0,stream>>>(BA,desrc,drowptr,dis,b5,out_x2);

  // Ac = S^T A S (no global atomics, no memset), then adj_out = S Ac S^T
  k_ac2<<<KK,256,0,stream>>>(cptr,colu,cval,esptr,esdst,srowptr,spair,Ac);
  k_adj<<<NN/4,1024,0,stream>>>(Ac,srowptr,spair,adj);
}

// Round 5
// 1118.396 us; speedup vs baseline: 2.0395x; 1.0806x over previous
//
#include <hip/hip_runtime.h>
#include <math.h>

#define NN 8192
#define EE 131072
#define ELn 139264   // EE + NN (edges + self loops)
#define HH 128
#define KK 4096

__device__ __forceinline__ int esrc(const int* __restrict__ edges, int e){ return e < EE ? edges[e] : e - EE; }
__device__ __forceinline__ int edst(const int* __restrict__ edges, int e){ return e < EE ? edges[EE + e] : e - EE; }

// ---------- degree counts (in + out fused) ----------
__global__ void k_count(const int* __restrict__ edges, int* __restrict__ indeg, int* __restrict__ outdeg){
  int e = blockIdx.x*blockDim.x + threadIdx.x;
  if (e < ELn){
    atomicAdd(&indeg[edst(edges,e)], 1);
    atomicAdd(&outdeg[esrc(edges,e)], 1);
  }
}

__global__ void k_dis(const int* __restrict__ deg, float* __restrict__ dis){
  int v = blockIdx.x*blockDim.x + threadIdx.x;
  if (v < NN){ float d = (float)deg[v]; d = d < 1.0f ? 1.0f : d; dis[v] = 1.0f/sqrtf(d); }
}

// single-block exclusive scan over 1024*IPT counts -> rowptr, cursor copy
template<int IPT>
__global__ __launch_bounds__(1024) void k_scan(const int* __restrict__ cnt, int* __restrict__ rowptr, int* __restrict__ cur){
  __shared__ int part[1024];
  int tid = threadIdx.x;
  int base = tid*IPT;
  int loc[IPT]; int s=0;
  #pragma unroll
  for (int i=0;i<IPT;i++) loc[i]=cnt[base+i];
  #pragma unroll
  for (int i=0;i<IPT;i++){ int t=loc[i]; loc[i]=s; s+=t; }
  part[tid]=s;
  __syncthreads();
  for (int off=1; off<1024; off<<=1){
    int v = (tid>=off)? part[tid-off] : 0;
    __syncthreads();
    part[tid]+=v;
    __syncthreads();
  }
  int cb = part[tid]-s;
  #pragma unroll
  for (int i=0;i<IPT;i++){ int r=cb+loc[i]; rowptr[base+i]=r; cur[base+i]=r; }
  if (tid==1023) rowptr[1024*IPT]=part[1023];
}

__global__ void k_fill_dst(const int* __restrict__ edges, int* __restrict__ cur,
                           int* __restrict__ delist, int* __restrict__ desrc){
  int e = blockIdx.x*blockDim.x + threadIdx.x;
  if (e < ELn){
    int v = edst(edges,e);
    int pos = atomicAdd(&cur[v],1);
    delist[pos] = e;
    desrc[pos]  = esrc(edges,e);
  }
}
__global__ void k_fill_src(const int* __restrict__ edges, int* __restrict__ cur, int* __restrict__ esdst){
  int e = blockIdx.x*blockDim.x + threadIdx.x;
  if (e < ELn){
    int u = esrc(edges,e);
    int pos = atomicAdd(&cur[u],1);
    esdst[pos] = edst(edges,e);
  }
}

// ---------- fused GCN layer: out[v,:] = act( (dis_v * sum_{u->v} dis_u x[u,:]) @ W + b ) ----------
// (uses linearity: segsum((x@W)[src]*norm) == segsum(x[src]*norm) @ W)
template<int TANH>
__global__ __launch_bounds__(256) void k_layer(const float* __restrict__ x,
    const int* __restrict__ desrc, const int* __restrict__ drowptr,
    const float* __restrict__ dis, const float* __restrict__ W,
    const float* __restrict__ bias, float* __restrict__ out){
  __shared__ float agg[8][HH];
  int tid = threadIdx.x;
  int r0 = blockIdx.x*8;
  int wv = tid>>6, lane = tid&63;
  // stage 1: aggregate 8 rows (2 per wave)
  for (int rr=wv; rr<8; rr+=4){
    int v = r0+rr;
    int beg = drowptr[v], end = drowptr[v+1];
    float ax=0.f, ay=0.f;
    for (int i=beg;i<end;++i){
      int u = desrc[i];
      float du = dis[u];
      float2 xv = *(const float2*)&x[(size_t)u*HH + lane*2];
      ax += du*xv.x; ay += du*xv.y;
    }
    float dv = dis[v];
    *(float2*)&agg[rr][lane*2] = make_float2(ax*dv, ay*dv);
  }
  __syncthreads();
  // stage 2: [8xHH] @ [HHxHH] from LDS
  int c = tid&127, h = tid>>7;
  float a0=0,a1=0,a2=0,a3=0;
  #pragma unroll 4
  for (int k=0;k<HH;++k){
    float wv_ = W[k*HH+c];
    a0 += agg[h*4+0][k]*wv_;
    a1 += agg[h*4+1][k]*wv_;
    a2 += agg[h*4+2][k]*wv_;
    a3 += agg[h*4+3][k]*wv_;
  }
  float b = bias[c];
  float r[4]={a0+b,a1+b,a2+b,a3+b};
  #pragma unroll
  for (int j=0;j<4;j++){
    float v = r[j];
    if (TANH) v = tanhf(v);
    out[(size_t)(r0+h*4+j)*HH + c] = v;
  }
}

// ---------- fp32 GEMM: y = x @ W + bias ; 8 rows/block (for wq) ----------
__global__ __launch_bounds__(256) void k_gemm8(const float* __restrict__ x, const float* __restrict__ W,
     const float* __restrict__ bias, float* __restrict__ y){
  __shared__ float xl[8*HH];
  int tid = threadIdx.x;
  int r0 = blockIdx.x*8;
  {
    int row = tid>>5, col = (tid&31)*4;
    *(float4*)&xl[row*HH+col] = *(const float4*)&x[(size_t)(r0+row)*HH+col];
  }
  __syncthreads();
  int c = tid & 127, h = tid>>7;
  float acc0=0,acc1=0,acc2=0,acc3=0;
  const float* xr = &xl[h*4*HH];
  #pragma unroll 8
  for (int k=0;k<HH;++k){
    float wv = W[k*HH+c];
    acc0 += xr[k]*wv;
    acc1 += xr[HH+k]*wv;
    acc2 += xr[2*HH+k]*wv;
    acc3 += xr[3*HH+k]*wv;
  }
  float b = bias[c];
  y[(size_t)(r0+h*4+0)*HH + c] = acc0+b;
  y[(size_t)(r0+h*4+1)*HH + c] = acc1+b;
  y[(size_t)(r0+h*4+2)*HH + c] = acc2+b;
  y[(size_t)(r0+h*4+3)*HH + c] = acc3+b;
}

// ---------- segment max over in-edges ----------
__global__ void k_segmax(const float* __restrict__ h, const int* __restrict__ desrc,
    const int* __restrict__ drowptr, float* __restrict__ out){
  int v = blockIdx.x, f = threadIdx.x;
  int beg = drowptr[v], end = drowptr[v+1];
  float m = -3.4e38f;
  for (int i=beg;i<end;++i){
    int u = desrc[i];
    m = fmaxf(m, h[(size_t)u*HH+f]);
  }
  out[(size_t)v*HH+f] = m;
}

// ---------- attention dots ----------
__global__ void k_aqah(const float* __restrict__ xq, const float* __restrict__ h,
                       const float* __restrict__ att, float* __restrict__ aq, float* __restrict__ ah){
  int v = blockIdx.x, t = threadIdx.x;
  float a1 = xq[(size_t)v*HH+t]*att[t];
  float a2 = h[(size_t)v*HH+t]*att[HH+t];
  #pragma unroll
  for (int off=32; off; off>>=1){ a1 += __shfl_down(a1,off); a2 += __shfl_down(a2,off); }
  __shared__ float s1[2], s2[2];
  if ((t&63)==0){ s1[t>>6]=a1; s2[t>>6]=a2; }
  __syncthreads();
  if (t==0){ aq[v]=s1[0]+s1[1]; ah[v]=s2[0]+s2[1]; }
}

// ---------- per-dst softmax -> alpha[e] (wave per node) ----------
__global__ __launch_bounds__(256) void k_alpha(const int* __restrict__ delist, const int* __restrict__ desrc,
    const int* __restrict__ drowptr, const float* __restrict__ aq, const float* __restrict__ ah,
    float* __restrict__ alpha){
  int v = blockIdx.x*4 + (threadIdx.x>>6);
  int lane = threadIdx.x & 63;
  int beg = drowptr[v], end = drowptr[v+1];
  float aqv = aq[v];
  float m = -3.4e38f;
  for (int i=beg+lane; i<end; i+=64){
    float s = aqv + ah[desrc[i]];
    s = s > 0.0f ? s : 0.2f*s;
    m = fmaxf(m, s);
  }
  #pragma unroll
  for (int off=32; off; off>>=1) m = fmaxf(m, __shfl_xor(m, off));
  float den = 0.0f;
  for (int i=beg+lane; i<end; i+=64){
    float s = aqv + ah[desrc[i]];
    s = s > 0.0f ? s : 0.2f*s;
    den += expf(s - m);
  }
  #pragma unroll
  for (int off=32; off; off>>=1) den += __shfl_xor(den, off);
  float inv = 1.0f/den;
  for (int i=beg+lane; i<end; i+=64){
    float s = aqv + ah[desrc[i]];
    s = s > 0.0f ? s : 0.2f*s;
    alpha[delist[i]] = expf(s - m)*inv;
  }
}

// ---------- cx[v] = sum_in alpha[e]*h[src] ----------
__global__ void k_cx(const float* __restrict__ h, const int* __restrict__ delist,
    const int* __restrict__ desrc, const int* __restrict__ drowptr,
    const float* __restrict__ alpha, float* __restrict__ cx){
  int v = blockIdx.x, f = threadIdx.x;
  int beg = drowptr[v], end = drowptr[v+1];
  float acc = 0.0f;
  for (int i=beg;i<end;++i){
    acc += alpha[delist[i]]*h[(size_t)desrc[i]*HH+f];
  }
  cx[(size_t)v*HH+f] = acc;
}

// ---------- LEConv dots ----------
__global__ void k_le(const float* __restrict__ cx, const float* __restrict__ lw1,
                     const float* __restrict__ lw2, const float* __restrict__ lw3,
                     float* __restrict__ l1, float* __restrict__ l2, float* __restrict__ l3){
  int v = blockIdx.x, t = threadIdx.x;
  float cv = cx[(size_t)v*HH+t];
  float a = cv*lw1[t], b = cv*lw2[t], c = cv*lw3[t];
  #pragma unroll
  for (int off=32; off; off>>=1){ a += __shfl_down(a,off); b += __shfl_down(b,off); c += __shfl_down(c,off); }
  __shared__ float sa[2], sb[2], sc[2];
  if ((t&63)==0){ sa[t>>6]=a; sb[t>>6]=b; sc[t>>6]=c; }
  __syncthreads();
  if (t==0){ l1[v]=sa[0]+sa[1]; l2[v]=sb[0]+sb[1]; l3[v]=sc[0]+sc[1]; }
}

__global__ __launch_bounds__(256) void k_fit(const int* __restrict__ desrc, const int* __restrict__ drowptr,
    const float* __restrict__ l1, const float* __restrict__ l2, const float* __restrict__ l3,
    const float* __restrict__ lb1, float* __restrict__ fit){
  int v = blockIdx.x*4 + (threadIdx.x>>6);
  int lane = threadIdx.x & 63;
  int beg = drowptr[v], end = drowptr[v+1];
  float s = 0.0f;
  for (int i=beg+lane;i<end;i+=64) s += l3[desrc[i]];
  #pragma unroll
  for (int off=32; off; off>>=1) s += __shfl_xor(s, off);
  if (lane==0){
    float degf = (float)(end-beg);
    float x = l1[v] + lb1[0] + degf*l2[v] - s;
    fit[v] = 1.0f/(1.0f+expf(-x));
  }
}

// ---------- top-K via single-block bitonic sort (set-exact; order irrelevant downstream) ----------
__global__ __launch_bounds__(1024) void k_topk(const float* __restrict__ fit, int* __restrict__ perm,
                        float* __restrict__ fitk, int* __restrict__ inv){
  __shared__ unsigned long long keys[NN];
  int tid = threadIdx.x;
  for (int i=tid;i<NN;i+=1024){
    unsigned u = __float_as_uint(fit[i]);
    unsigned mono = (u>>31) ? ~u : (u|0x80000000u);
    keys[i] = ((unsigned long long)(~mono)<<32) | (unsigned)i;
    inv[i] = -1;
  }
  __syncthreads();
  for (int k=2;k<=NN;k<<=1)
    for (int j=k>>1;j>0;j>>=1){
      for (int t=tid;t<NN;t+=1024){
        int ixj = t^j;
        if (ixj > t){
          bool up = ((t&k)==0);
          unsigned long long a = keys[t], b = keys[ixj];
          if (up ? (a>b) : (a<b)){ keys[t]=b; keys[ixj]=a; }
        }
      }
      __syncthreads();
    }
  for (int i=tid;i<KK;i+=1024){
    int idx = (int)(keys[i] & 0xffffffffu);
    perm[i]=idx; fitk[i]=fit[idx]; inv[idx]=i;
  }
}

__global__ void k_xp(const float* __restrict__ cx, const int* __restrict__ perm,
                     const float* __restrict__ fitk, float* __restrict__ xp){
  int j = blockIdx.x, f = threadIdx.x;
  xp[(size_t)j*HH+f] = cx[(size_t)perm[j]*HH+f]*fitk[j];
}

// ---------- S (CSR by src) ----------
__global__ void k_scnt(const int* __restrict__ edges, const int* __restrict__ inv, int* __restrict__ scnt){
  int e = blockIdx.x*blockDim.x + threadIdx.x;
  if (e < ELn && inv[edst(edges,e)] >= 0) atomicAdd(&scnt[esrc(edges,e)],1);
}

__global__ void k_fill_s(const int* __restrict__ edges, const int* __restrict__ inv,
                         const float* __restrict__ alpha, int* __restrict__ scur,
                         int2* __restrict__ spair, int* __restrict__ srow_of){
  int e = blockIdx.x*blockDim.x + threadIdx.x;
  if (e < ELn){
    int j = inv[edst(edges,e)];
    if (j >= 0){
      int u = esrc(edges,e);
      int pos = atomicAdd(&scur[u],1);
      spair[pos] = make_int2(j, __float_as_int(alpha[e]));
      srow_of[pos] = u;
    }
  }
}

// ---------- CSC of S by column ----------
__global__ void k_col_cnt(const int2* __restrict__ spair, const int* __restrict__ srowptr, int* __restrict__ ccnt){
  int i = blockIdx.x*blockDim.x + threadIdx.x;
  if (i < srowptr[NN]) atomicAdd(&ccnt[spair[i].x], 1);
}
__global__ void k_col_fill(const int2* __restrict__ spair, const int* __restrict__ srow_of,
                           const int* __restrict__ srowptr, int* __restrict__ ccur,
                           int* __restrict__ colu, float* __restrict__ cval){
  int i = blockIdx.x*blockDim.x + threadIdx.x;
  if (i < srowptr[NN]){
    int2 p = spair[i];
    int pos = atomicAdd(&ccur[p.x], 1);
    colu[pos] = srow_of[i];
    cval[pos] = __int_as_float(p.y);
  }
}

// ---------- x_out = S @ xp ----------
__global__ void k_xout(const float* __restrict__ xp, const int* __restrict__ srowptr,
                       const int2* __restrict__ spair, float* __restrict__ xout){
  int u = blockIdx.x, f = threadIdx.x;
  int beg = srowptr[u], end = srowptr[u+1];
  float acc = 0.0f;
  for (int i=beg;i<end;++i){
    int2 p = spair[i];
    acc += __int_as_float(p.y)*xp[(size_t)p.x*HH+f];
  }
  xout[(size_t)u*HH+f] = acc;
}

// ---------- Ac row p = sum_{(u,val) in col p of S} val * sum_{v in outN(u)} S[v,:] ----------
#define ACCAP 2048
__global__ __launch_bounds__(256) void k_ac2(const int* __restrict__ cptr, const int* __restrict__ colu,
     const float* __restrict__ cval, const int* __restrict__ esptr, const int* __restrict__ esdst,
     const int* __restrict__ srowptr, const int2* __restrict__ spair, float* __restrict__ Ac){
  __shared__ float row[KK];
  __shared__ int   lv[ACCAP];
  __shared__ float lval[ACCAP];
  int tid = threadIdx.x;
  int p = blockIdx.x;
  for (int i=tid;i<KK;i+=256) row[i]=0.0f;
  int cb = cptr[p], ce = cptr[p+1];
  int base = 0;
  int j = cb;
  while (true){
    while (j < ce){
      int u = colu[j]; float val = cval[j];
      int eb = esptr[u], d = esptr[u+1]-eb;
      if (base + d > ACCAP) break;
      for (int t=tid; t<d; t+=256){ lv[base+t]=esdst[eb+t]; lval[base+t]=val; }
      base += d; ++j;
    }
    __syncthreads();
    for (int i=tid;i<base;i+=256){
      int v = lv[i]; float a = lval[i];
      int sb = srowptr[v], se = srowptr[v+1];
      for (int k=sb;k<se;++k){
        int2 q = spair[k];
        atomicAdd(&row[q.x], a*__int_as_float(q.y));
      }
    }
    __syncthreads();
    base = 0;
    if (j >= ce) break;
  }
  for (int i=tid;i<KK;i+=256) Ac[(size_t)p*KK+i] = row[i];
}

// ---------- adj_out = S Ac S^T, fused; 8 rows/block, 1024 threads, U in LDS [g][q] (128 KB) ----------
__global__ __launch_bounds__(1024) void k_adj(const float* __restrict__ Ac, const int* __restrict__ srowptr,
      const int2* __restrict__ spair, float* __restrict__ adj){
  __shared__ float U[8*KK];  // 128 KB, [g][q]
  int tid = threadIdx.x;
  int u0 = blockIdx.x*8;
  // phase 1: U[g][q] = sum_p S[u0+g,p] * Ac[p,q]; thread owns q = 4*tid..4*tid+3
  #pragma unroll
  for (int g=0; g<8; ++g){
    int beg = srowptr[u0+g], end = srowptr[u0+g+1];
    float ux=0.f, uy=0.f, uz=0.f, uw=0.f;
    for (int i=beg;i<end;++i){
      int2 pr = spair[i];               // broadcast
      float a = __int_as_float(pr.y);
      float4 av = *(const float4*)(Ac + (size_t)pr.x*KK + 4*tid);
      ux += a*av.x; uy += a*av.y; uz += a*av.z; uw += a*av.w;
    }
    *(float4*)&U[g*KK + 4*tid] = make_float4(ux,uy,uz,uw);   // coalesced ds_write_b128
  }
  __syncthreads();
  // phase 2: adj[u0+g][w] = sum_q S[w,q] * U[g][q]; 8 b32 LDS reads (bank = q%32, ~conflict-free)
  for (int wb=0; wb<NN; wb+=1024){
    int w = wb + tid;
    int beg = srowptr[w], end = srowptr[w+1];
    float acc[8];
    #pragma unroll
    for (int g=0;g<8;g++) acc[g]=0.f;
    for (int i=beg;i<end;++i){
      int2 p = spair[i];
      float b = __int_as_float(p.y);
      int q = p.x;
      #pragma unroll
      for (int g=0;g<8;g++) acc[g] += b*U[g*KK+q];
    }
    #pragma unroll
    for (int g=0;g<8;g++)
      __builtin_nontemporal_store(acc[g], &adj[(size_t)(u0+g)*NN + w]);
  }
}

extern "C" void kernel_launch(void* const* d_in, const int* in_sizes, int n_in,
                              void* d_out, int out_size, void* d_ws, size_t ws_size,
                              hipStream_t stream){
  const float* nodes = (const float*)d_in[0];
  const int*   edges = (const int*)d_in[1];
  const float* w1=(const float*)d_in[3];  const float* b1=(const float*)d_in[4];
  const float* w2=(const float*)d_in[5];  const float* b2=(const float*)d_in[6];
  const float* w3=(const float*)d_in[7];  const float* b3=(const float*)d_in[8];
  const float* w4=(const float*)d_in[9];  const float* b4=(const float*)d_in[10];
  const float* w5=(const float*)d_in[11]; const float* b5=(const float*)d_in[12];
  const float* wq=(const float*)d_in[13]; const float* bq=(const float*)d_in[14];
  const float* att=(const float*)d_in[15];
  const float* lw1=(const float*)d_in[16]; const float* lb1=(const float*)d_in[17];
  const float* lw2=(const float*)d_in[18]; const float* lw3=(const float*)d_in[19];

  // ---- workspace layout (d_ws) ----
  char* ws = (char*)d_ws;
  size_t off = 0;
  auto take = [&](size_t bytes)->char*{
    char* p = ws + off;
    off = (off + bytes + 255) & ~(size_t)255;
    return p;
  };
  int*   deg     = (int*)  take((size_t)NN*4);
  float* dis     = (float*)take((size_t)NN*4);
  int*   drowptr = (int*)  take((size_t)(NN+1)*4);
  int*   dcur    = (int*)  take((size_t)NN*4);
  int*   delist  = (int*)  take((size_t)ELn*4);
  float* alpha   = (float*)take((size_t)ELn*4);
  float* aq      = (float*)take((size_t)NN*4);
  float* ah      = (float*)take((size_t)NN*4);
  float* l1      = (float*)take((size_t)NN*4);
  float* l2      = (float*)take((size_t)NN*4);
  float* l3      = (float*)take((size_t)NN*4);
  float* fit     = (float*)take((size_t)NN*4);
  int*   perm    = (int*)  take((size_t)KK*4);
  float* fitk    = (float*)take((size_t)KK*4);
  int*   inv     = (int*)  take((size_t)NN*4);
  int*   scnt    = (int*)  take((size_t)NN*4);
  int*   srowptr = (int*)  take((size_t)(NN+1)*4);
  int*   scur    = (int*)  take((size_t)NN*4);
  int2*  spair   = (int2*) take((size_t)ELn*8);
  int*   ecnt    = (int*)  take((size_t)NN*4);
  int*   esptr   = (int*)  take((size_t)(NN+1)*4);
  int*   ecur    = (int*)  take((size_t)NN*4);
  int*   ccnt    = (int*)  take((size_t)KK*4);
  int*   cptr    = (int*)  take((size_t)(KK+1)*4);
  int*   ccur    = (int*)  take((size_t)KK*4);
  float* Ac      = (float*)take((size_t)KK*KK*4);
  (void)ws_size; (void)in_sizes; (void)n_in; (void)out_size;

  // ---- big node buffers live in d_out's adj region (overwritten last by k_adj) ----
  float* out_x2 = (float*)d_out;                       // [NN,HH]
  float* adj    = (float*)d_out + (size_t)NN*HH;       // [NN,NN]
  float* BB = adj + 0*(size_t)NN*HH;  // h1 / h3
  float* BC = adj + 1*(size_t)NN*HH;  // h (post GCN2)
  float* BD = adj + 2*(size_t)NN*HH;  // segmax out / h4
  float* BE = adj + 3*(size_t)NN*HH;  // xq
  float* BF = adj + 4*(size_t)NN*HH;  // cx
  float* BG = adj + 5*(size_t)NN*HH;  // x_out
  float* xp = adj + 6*(size_t)NN*HH;  // [KK,HH]
  char*  sc2 = (char*)(adj + 7*(size_t)NN*HH);
  int*   desrc   = (int*)  sc2;                       sc2 += (size_t)ELn*4;
  int*   esdst   = (int*)  sc2;                       sc2 += (size_t)ELn*4;
  int*   srow_of = (int*)  sc2;                       sc2 += (size_t)ELn*4;
  int*   colu    = (int*)  sc2;                       sc2 += (size_t)ELn*4;
  float* cval    = (float*)sc2;                       sc2 += (size_t)ELn*4;

  const int EB = ELn/256;  // 544 exact

  // degree + CSR-by-dst + CSR-by-src
  hipMemsetAsync(deg, 0, (size_t)NN*4, stream);
  hipMemsetAsync(ecnt, 0, (size_t)NN*4, stream);
  k_count<<<EB,256,0,stream>>>(edges,deg,ecnt);
  k_dis<<<NN/256,256,0,stream>>>(deg,dis);
  k_scan<8><<<1,1024,0,stream>>>(deg,drowptr,dcur);
  k_fill_dst<<<EB,256,0,stream>>>(edges,dcur,delist,desrc);
  k_scan<8><<<1,1024,0,stream>>>(ecnt,esptr,ecur);
  k_fill_src<<<EB,256,0,stream>>>(edges,ecur,esdst);

  // GCN1, GCN2 (fused aggregate+gemm+tanh)
  k_layer<1><<<NN/8,256,0,stream>>>(nodes,desrc,drowptr,dis,w1,b1,BB);
  k_layer<1><<<NN/8,256,0,stream>>>(BB,desrc,drowptr,dis,w2,b2,BC);

  // ASAP pooling
  k_segmax<<<NN,128,0,stream>>>(BC,desrc,drowptr,BD);
  k_gemm8<<<NN/8,256,0,stream>>>(BD,wq,bq,BE);
  k_aqah<<<NN,128,0,stream>>>(BE,BC,att,aq,ah);
  k_alpha<<<NN/4,256,0,stream>>>(delist,desrc,drowptr,aq,ah,alpha);
  k_cx<<<NN,128,0,stream>>>(BC,delist,desrc,drowptr,alpha,BF);
  k_le<<<NN,128,0,stream>>>(BF,lw1,lw2,lw3,l1,l2,l3);
  k_fit<<<NN/4,256,0,stream>>>(desrc,drowptr,l1,l2,l3,lb1,fit);
  k_topk<<<1,1024,0,stream>>>(fit,perm,fitk,inv);
  k_xp<<<KK,128,0,stream>>>(BF,perm,fitk,xp);

  // S CSR (by src) + CSC (by col)
  hipMemsetAsync(scnt, 0, (size_t)NN*4, stream);
  k_scnt<<<EB,256,0,stream>>>(edges,inv,scnt);
  k_scan<8><<<1,1024,0,stream>>>(scnt,srowptr,scur);
  k_fill_s<<<EB,256,0,stream>>>(edges,inv,alpha,scur,spair,srow_of);
  hipMemsetAsync(ccnt, 0, (size_t)KK*4, stream);
  k_col_cnt<<<EB,256,0,stream>>>(spair,srowptr,ccnt);
  k_scan<4><<<1,1024,0,stream>>>(ccnt,cptr,ccur);
  k_col_fill<<<EB,256,0,stream>>>(spair,srow_of,srowptr,ccur,colu,cval);

  // x_out = S @ xp, then GCN3/4/5 -> x2 (first chunk of d_out)
  k_xout<<<NN,128,0,stream>>>(xp,srowptr,spair,BG);
  k_layer<1><<<NN/8,256,0,stream>>>(BG,desrc,drowptr,dis,w3,b3,BB);
  k_layer<1><<<NN/8,256,0,stream>>>(BB,desrc,drowptr,dis,w4,b4,BD);
  k_layer<0><<<NN/8,256,0,stream>>>(BD,desrc,drowptr,dis,w5,b5,out_x2);

  // Ac = S^T A S (no global atomics), then adj_out = S Ac S^T
  k_ac2<<<KK,256,0,stream>>>(cptr,colu,cval,esptr,esdst,srowptr,spair,Ac);
  k_adj<<<NN/8,1024,0,stream>>>(Ac,srowptr,spair,adj);
}

// Round 6
// 1026.464 us; speedup vs baseline: 2.2222x; 1.0896x over previous
//
#include <hip/hip_runtime.h>
#include <math.h>

#define NN 8192
#define EE 131072
#define ELn 139264   // EE + NN (edges + self loops)
#define HH 128
#define KK 4096
#define NBIN 65536

__device__ __forceinline__ int esrc(const int* __restrict__ edges, int e){ return e < EE ? edges[e] : e - EE; }
__device__ __forceinline__ int edst(const int* __restrict__ edges, int e){ return e < EE ? edges[EE + e] : e - EE; }

// ---------- degree counts (in + out fused) ----------
__global__ void k_count(const int* __restrict__ edges, int* __restrict__ indeg, int* __restrict__ outdeg){
  int e = blockIdx.x*blockDim.x + threadIdx.x;
  if (e < ELn){
    atomicAdd(&indeg[edst(edges,e)], 1);
    atomicAdd(&outdeg[esrc(edges,e)], 1);
  }
}

__global__ void k_dis(const int* __restrict__ deg, float* __restrict__ dis){
  int v = blockIdx.x*blockDim.x + threadIdx.x;
  if (v < NN){ float d = (float)deg[v]; d = d < 1.0f ? 1.0f : d; dis[v] = 1.0f/sqrtf(d); }
}

// single-block exclusive scan over 1024*IPT counts -> rowptr, cursor copy
template<int IPT>
__device__ __forceinline__ void scan_body(const int* __restrict__ cnt, int* __restrict__ rowptr, int* __restrict__ cur){
  __shared__ int part[1024];
  int tid = threadIdx.x;
  int base = tid*IPT;
  int loc[IPT]; int s=0;
  #pragma unroll
  for (int i=0;i<IPT;i++) loc[i]=cnt[base+i];
  #pragma unroll
  for (int i=0;i<IPT;i++){ int t=loc[i]; loc[i]=s; s+=t; }
  part[tid]=s;
  __syncthreads();
  for (int off=1; off<1024; off<<=1){
    int v = (tid>=off)? part[tid-off] : 0;
    __syncthreads();
    part[tid]+=v;
    __syncthreads();
  }
  int cb = part[tid]-s;
  #pragma unroll
  for (int i=0;i<IPT;i++){ int r=cb+loc[i]; rowptr[base+i]=r; cur[base+i]=r; }
  if (tid==1023) rowptr[1024*IPT]=part[1023];
}
template<int IPT>
__global__ __launch_bounds__(1024) void k_scan(const int* __restrict__ cnt, int* __restrict__ rowptr, int* __restrict__ cur){
  scan_body<IPT>(cnt, rowptr, cur);
}
// two independent scans in one launch (block 0 / block 1)
__global__ __launch_bounds__(1024) void k_scan2(const int* __restrict__ c0, int* __restrict__ r0, int* __restrict__ u0,
                                                const int* __restrict__ c1, int* __restrict__ r1, int* __restrict__ u1){
  if (blockIdx.x==0) scan_body<8>(c0,r0,u0);
  else               scan_body<8>(c1,r1,u1);
}

// fill CSR-by-dst and CSR-by-src in one pass
__global__ void k_fill_both(const int* __restrict__ edges, int* __restrict__ dcur, int* __restrict__ ecur,
                            int* __restrict__ delist, int* __restrict__ desrc, int* __restrict__ esdst){
  int e = blockIdx.x*blockDim.x + threadIdx.x;
  if (e < ELn){
    int v = edst(edges,e), u = esrc(edges,e);
    int pos = atomicAdd(&dcur[v],1);
    delist[pos] = e;
    desrc[pos]  = u;
    int pos2 = atomicAdd(&ecur[u],1);
    esdst[pos2] = v;
  }
}

// ---------- fused GCN layer: out[v,:] = act( (dis_v * sum_{u->v} dis_u x[u,:]) @ W + b ) ----------
// AH: also emit ah[v] = sum_c out[v,c]*att[HH+c]
template<int TANH, int AH>
__global__ __launch_bounds__(256) void k_layer(const float* __restrict__ x,
    const int* __restrict__ desrc, const int* __restrict__ drowptr,
    const float* __restrict__ dis, const float* __restrict__ W,
    const float* __restrict__ bias, const float* __restrict__ att,
    float* __restrict__ out, float* __restrict__ ah){
  __shared__ float agg[8][HH];
  __shared__ float sred[4][4];
  int tid = threadIdx.x;
  int r0 = blockIdx.x*8;
  int wvid = tid>>6, lane = tid&63;
  for (int rr=wvid; rr<8; rr+=4){
    int v = r0+rr;
    int beg = drowptr[v], end = drowptr[v+1];
    float ax=0.f, ay=0.f;
    for (int i=beg;i<end;++i){
      int u = desrc[i];
      float du = dis[u];
      float2 xv = *(const float2*)&x[(size_t)u*HH + lane*2];
      ax += du*xv.x; ay += du*xv.y;
    }
    float dv = dis[v];
    *(float2*)&agg[rr][lane*2] = make_float2(ax*dv, ay*dv);
  }
  __syncthreads();
  int c = tid&127, h = tid>>7;
  float a0=0,a1=0,a2=0,a3=0;
  #pragma unroll 4
  for (int k=0;k<HH;++k){
    float wv_ = W[k*HH+c];
    a0 += agg[h*4+0][k]*wv_;
    a1 += agg[h*4+1][k]*wv_;
    a2 += agg[h*4+2][k]*wv_;
    a3 += agg[h*4+3][k]*wv_;
  }
  float b = bias[c];
  float tv[4]={a0+b,a1+b,a2+b,a3+b};
  #pragma unroll
  for (int j=0;j<4;j++){
    if (TANH) tv[j] = tanhf(tv[j]);
    out[(size_t)(r0+h*4+j)*HH + c] = tv[j];
  }
  if (AH){
    float ac = att[HH+c];
    float s0=tv[0]*ac, s1=tv[1]*ac, s2=tv[2]*ac, s3=tv[3]*ac;
    #pragma unroll
    for (int off=32; off; off>>=1){
      s0 += __shfl_down(s0,off); s1 += __shfl_down(s1,off);
      s2 += __shfl_down(s2,off); s3 += __shfl_down(s3,off);
    }
    if (lane==0){ sred[wvid][0]=s0; sred[wvid][1]=s1; sred[wvid][2]=s2; sred[wvid][3]=s3; }
    __syncthreads();
    if (tid<8){ // row r0+tid: h=tid>>2 -> waves 2h,2h+1 ; j=tid&3
      int hh = tid>>2, j = tid&3;
      ah[r0+tid] = sred[hh*2][j] + sred[hh*2+1][j];
    }
  }
}

// ---------- pool: segmax over in-edges -> xq = max@wq+bq -> aq[v]=xq.att[:H] (xq never materialized) ----------
__global__ __launch_bounds__(256) void k_pool(const float* __restrict__ hx,
    const int* __restrict__ desrc, const int* __restrict__ drowptr,
    const float* __restrict__ wq, const float* __restrict__ bq,
    const float* __restrict__ att, float* __restrict__ aq){
  __shared__ float agg[8][HH];
  __shared__ float sred[4][4];
  int tid = threadIdx.x;
  int r0 = blockIdx.x*8;
  int wvid = tid>>6, lane = tid&63;
  for (int rr=wvid; rr<8; rr+=4){
    int v = r0+rr;
    int beg = drowptr[v], end = drowptr[v+1];
    float mx=-3.4e38f, my=-3.4e38f;
    for (int i=beg;i<end;++i){
      int u = desrc[i];
      float2 xv = *(const float2*)&hx[(size_t)u*HH + lane*2];
      mx = fmaxf(mx, xv.x); my = fmaxf(my, xv.y);
    }
    *(float2*)&agg[rr][lane*2] = make_float2(mx, my);
  }
  __syncthreads();
  int c = tid&127, h = tid>>7;
  float a0=0,a1=0,a2=0,a3=0;
  #pragma unroll 4
  for (int k=0;k<HH;++k){
    float wv_ = wq[k*HH+c];
    a0 += agg[h*4+0][k]*wv_;
    a1 += agg[h*4+1][k]*wv_;
    a2 += agg[h*4+2][k]*wv_;
    a3 += agg[h*4+3][k]*wv_;
  }
  float b = bq[c], ac = att[c];
  float s0=(a0+b)*ac, s1=(a1+b)*ac, s2=(a2+b)*ac, s3=(a3+b)*ac;
  #pragma unroll
  for (int off=32; off; off>>=1){
    s0 += __shfl_down(s0,off); s1 += __shfl_down(s1,off);
    s2 += __shfl_down(s2,off); s3 += __shfl_down(s3,off);
  }
  if (lane==0){ sred[wvid][0]=s0; sred[wvid][1]=s1; sred[wvid][2]=s2; sred[wvid][3]=s3; }
  __syncthreads();
  if (tid<8){
    int hh = tid>>2, j = tid&3;
    aq[r0+tid] = sred[hh*2][j] + sred[hh*2+1][j];
  }
}

// ---------- per-dst softmax -> alpha[e] (wave per node) ----------
__global__ __launch_bounds__(256) void k_alpha(const int* __restrict__ delist, const int* __restrict__ desrc,
    const int* __restrict__ drowptr, const float* __restrict__ aq, const float* __restrict__ ah,
    float* __restrict__ alpha){
  int v = blockIdx.x*4 + (threadIdx.x>>6);
  int lane = threadIdx.x & 63;
  int beg = drowptr[v], end = drowptr[v+1];
  float aqv = aq[v];
  float m = -3.4e38f;
  for (int i=beg+lane; i<end; i+=64){
    float s = aqv + ah[desrc[i]];
    s = s > 0.0f ? s : 0.2f*s;
    m = fmaxf(m, s);
  }
  #pragma unroll
  for (int off=32; off; off>>=1) m = fmaxf(m, __shfl_xor(m, off));
  float den = 0.0f;
  for (int i=beg+lane; i<end; i+=64){
    float s = aqv + ah[desrc[i]];
    s = s > 0.0f ? s : 0.2f*s;
    den += expf(s - m);
  }
  #pragma unroll
  for (int off=32; off; off>>=1) den += __shfl_xor(den, off);
  float inv = 1.0f/den;
  for (int i=beg+lane; i<end; i+=64){
    float s = aqv + ah[desrc[i]];
    s = s > 0.0f ? s : 0.2f*s;
    alpha[delist[i]] = expf(s - m)*inv;
  }
}

// ---------- cx[v] = sum_in alpha[e]*h[src] ; also l1/l2/l3 dots ----------
__global__ void k_cxle(const float* __restrict__ h, const int* __restrict__ delist,
    const int* __restrict__ desrc, const int* __restrict__ drowptr,
    const float* __restrict__ alpha, const float* __restrict__ lw1,
    const float* __restrict__ lw2, const float* __restrict__ lw3,
    float* __restrict__ cx, float* __restrict__ l1, float* __restrict__ l2, float* __restrict__ l3){
  int v = blockIdx.x, f = threadIdx.x;
  int beg = drowptr[v], end = drowptr[v+1];
  float acc = 0.0f;
  for (int i=beg;i<end;++i){
    acc += alpha[delist[i]]*h[(size_t)desrc[i]*HH+f];
  }
  cx[(size_t)v*HH+f] = acc;
  float p1 = acc*lw1[f], p2 = acc*lw2[f], p3 = acc*lw3[f];
  #pragma unroll
  for (int off=32; off; off>>=1){ p1 += __shfl_down(p1,off); p2 += __shfl_down(p2,off); p3 += __shfl_down(p3,off); }
  __shared__ float sa[2], sb[2], sc[2];
  if ((f&63)==0){ sa[f>>6]=p1; sb[f>>6]=p2; sc[f>>6]=p3; }
  __syncthreads();
  if (f==0){ l1[v]=sa[0]+sa[1]; l2[v]=sb[0]+sb[1]; l3[v]=sc[0]+sc[1]; }
}

// ---------- fit + histogram (fit>0 so float bits are monotone uint) ----------
__global__ __launch_bounds__(256) void k_fit(const int* __restrict__ desrc, const int* __restrict__ drowptr,
    const float* __restrict__ l1, const float* __restrict__ l2, const float* __restrict__ l3,
    const float* __restrict__ lb1, float* __restrict__ fit, int* __restrict__ hist){
  int v = blockIdx.x*4 + (threadIdx.x>>6);
  int lane = threadIdx.x & 63;
  int beg = drowptr[v], end = drowptr[v+1];
  float s = 0.0f;
  for (int i=beg+lane;i<end;i+=64) s += l3[desrc[i]];
  #pragma unroll
  for (int off=32; off; off>>=1) s += __shfl_xor(s, off);
  if (lane==0){
    float degf = (float)(end-beg);
    float x = l1[v] + lb1[0] + degf*l2[v] - s;
    float fv = 1.0f/(1.0f+expf(-x));
    fit[v] = fv;
    atomicAdd(&hist[__float_as_uint(fv)>>16], 1);
  }
}

// ---------- find cut bin B: count(key>>16 > B) < K <= +hist[B] ----------
__global__ __launch_bounds__(1024) void k_scanfind(const int* __restrict__ hist, int* __restrict__ meta){
  __shared__ int part[1024];
  int tid = threadIdx.x;
  int chunk = 0;
  #pragma unroll
  for (int i=0;i<NBIN/1024;i++) chunk += hist[tid*(NBIN/1024)+i];
  part[tid] = chunk;
  __syncthreads();
  for (int off=1; off<1024; off<<=1){
    int v = (tid+off<1024)? part[tid+off] : 0;
    __syncthreads();
    part[tid] += v;
    __syncthreads();
  }
  int cum = part[tid] - chunk;   // count in higher chunks
  for (int i=NBIN/1024-1; i>=0; --i){
    int b = tid*(NBIN/1024)+i;
    int c = hist[b];
    if (cum < KK && cum + c >= KK){ meta[2]=b; meta[3]=cum; }
    cum += c;
  }
}

// ---------- classify: definite winners get slots [0,nGT); tie-bin members collected ----------
__global__ void k_assign(const float* __restrict__ fit, const int* __restrict__ meta,
                         int* __restrict__ ctr, int* __restrict__ inv, unsigned long long* __restrict__ ties){
  int v = blockIdx.x*blockDim.x + threadIdx.x;
  if (v >= NN) return;
  unsigned key = __float_as_uint(fit[v]);
  int B = meta[2];
  int kb = (int)(key>>16);
  if (kb > B){
    inv[v] = atomicAdd(&ctr[0], 1);
  } else if (kb == B){
    int pos = atomicAdd(&ctr[1], 1);
    ties[pos] = ((unsigned long long)(~key)<<32) | (unsigned)v;  // sort asc => fit desc, idx asc
    inv[v] = -1;
  } else {
    inv[v] = -1;
  }
}

// ---------- sort tie bin (<=NN), first (K-nGT) get remaining slots ----------
__global__ __launch_bounds__(1024) void k_ties(const int* __restrict__ meta, const int* __restrict__ ctr,
                                               const unsigned long long* __restrict__ ties, int* __restrict__ inv){
  __shared__ unsigned long long keys[NN];
  int tid = threadIdx.x;
  int nt = ctr[1];
  int nGT = meta[3];
  int need = KK - nGT;
  int m = 1; while (m < nt) m <<= 1;
  if (m < 2) m = 2;
  for (int i=tid;i<m;i+=1024) keys[i] = (i<nt)? ties[i] : 0xFFFFFFFFFFFFFFFFull;
  __syncthreads();
  for (int k=2;k<=m;k<<=1)
    for (int j=k>>1;j>0;j>>=1){
      for (int t=tid;t<m;t+=1024){
        int ixj = t^j;
        if (ixj > t){
          bool up = ((t&k)==0);
          unsigned long long a = keys[t], b = keys[ixj];
          if (up ? (a>b) : (a<b)){ keys[t]=b; keys[ixj]=a; }
        }
      }
      __syncthreads();
    }
  for (int i=tid;i<need;i+=1024){
    int v = (int)(keys[i] & 0xffffffffu);
    inv[v] = nGT + i;
  }
}

// ---------- S (CSR by src) ----------
__global__ void k_scnt(const int* __restrict__ edges, const int* __restrict__ inv, int* __restrict__ scnt){
  int e = blockIdx.x*blockDim.x + threadIdx.x;
  if (e < ELn && inv[edst(edges,e)] >= 0) atomicAdd(&scnt[esrc(edges,e)],1);
}

__global__ void k_fill_s(const int* __restrict__ edges, const int* __restrict__ inv,
                         const float* __restrict__ alpha, int* __restrict__ scur,
                         int2* __restrict__ spair, int* __restrict__ srow_of, int* __restrict__ sdst_of){
  int e = blockIdx.x*blockDim.x + threadIdx.x;
  if (e < ELn){
    int d = edst(edges,e);
    int j = inv[d];
    if (j >= 0){
      int u = esrc(edges,e);
      int pos = atomicAdd(&scur[u],1);
      spair[pos] = make_int2(j, __float_as_int(alpha[e]));
      srow_of[pos] = u;
      sdst_of[pos] = d;
    }
  }
}

// ---------- CSC of S by column ----------
__global__ void k_col_cnt(const int2* __restrict__ spair, const int* __restrict__ srowptr, int* __restrict__ ccnt){
  int i = blockIdx.x*blockDim.x + threadIdx.x;
  if (i < srowptr[NN]) atomicAdd(&ccnt[spair[i].x], 1);
}
__global__ void k_col_fill(const int2* __restrict__ spair, const int* __restrict__ srow_of,
                           const int* __restrict__ srowptr, int* __restrict__ ccur,
                           int* __restrict__ colu, float* __restrict__ cval){
  int i = blockIdx.x*blockDim.x + threadIdx.x;
  if (i < srowptr[NN]){
    int2 p = spair[i];
    int pos = atomicAdd(&ccur[p.x], 1);
    colu[pos] = srow_of[i];
    cval[pos] = __int_as_float(p.y);
  }
}

// ---------- x_out[u] = sum entries val * fit[dst] * cx[dst,:]  (xp never materialized) ----------
__global__ void k_xout(const float* __restrict__ cx, const float* __restrict__ fit,
                       const int* __restrict__ srowptr, const int2* __restrict__ spair,
                       const int* __restrict__ sdst_of, float* __restrict__ xout){
  int u = blockIdx.x, f = threadIdx.x;
  int beg = srowptr[u], end = srowptr[u+1];
  float acc = 0.0f;
  for (int i=beg;i<end;++i){
    int d = sdst_of[i];
    acc += __int_as_float(spair[i].y)*fit[d]*cx[(size_t)d*HH+f];
  }
  xout[(size_t)u*HH+f] = acc;
}

// ---------- Ac row p = sum_{(u,val) in col p of S} val * sum_{v in outN(u)} S[v,:] ----------
#define ACCAP 2048
__global__ __launch_bounds__(256) void k_ac2(const int* __restrict__ cptr, const int* __restrict__ colu,
     const float* __restrict__ cval, const int* __restrict__ esptr, const int* __restrict__ esdst,
     const int* __restrict__ srowptr, const int2* __restrict__ spair, float* __restrict__ Ac){
  __shared__ float row[KK];
  __shared__ int   lv[ACCAP];
  __shared__ float lval[ACCAP];
  int tid = threadIdx.x;
  int p = blockIdx.x;
  for (int i=tid;i<KK;i+=256) row[i]=0.0f;
  int cb = cptr[p], ce = cptr[p+1];
  int base = 0;
  int j = cb;
  while (true){
    while (j < ce){
      int u = colu[j]; float val = cval[j];
      int eb = esptr[u], d = esptr[u+1]-eb;
      if (base + d > ACCAP) break;
      for (int t=tid; t<d; t+=256){ lv[base+t]=esdst[eb+t]; lval[base+t]=val; }
      base += d; ++j;
    }
    __syncthreads();
    for (int i=tid;i<base;i+=256){
      int v = lv[i]; float a = lval[i];
      int sb = srowptr[v], se = srowptr[v+1];
      for (int k=sb;k<se;++k){
        int2 q = spair[k];
        atomicAdd(&row[q.x], a*__int_as_float(q.y));
      }
    }
    __syncthreads();
    base = 0;
    if (j >= ce) break;
  }
  for (int i=tid;i<KK;i+=256) Ac[(size_t)p*KK+i] = row[i];
}

// ---------- adj_out = S Ac S^T, fused; 8 rows/block, 1024 threads, U in LDS [g][q] (128 KB) ----------
__global__ __launch_bounds__(1024) void k_adj(const float* __restrict__ Ac, const int* __restrict__ srowptr,
      const int2* __restrict__ spair, float* __restrict__ adj){
  __shared__ float U[8*KK];  // 128 KB, [g][q]
  int tid = threadIdx.x;
  int u0 = blockIdx.x*8;
  // phase 1: U[g][q] = sum_p S[u0+g,p] * Ac[p,q]; 2 rows interleaved for MLP
  #pragma unroll
  for (int g2=0; g2<8; g2+=2){
    int bA = srowptr[u0+g2],   eA = srowptr[u0+g2+1];
    int bB = eA,               eB = srowptr[u0+g2+2];
    float ax0=0,ax1=0,ax2=0,ax3=0, bx0=0,bx1=0,bx2=0,bx3=0;
    int nA = eA-bA, nB = eB-bB;
    int n = nA > nB ? nA : nB;
    for (int t=0;t<n;++t){
      if (t<nA){
        int2 pr = spair[bA+t];
        float a = __int_as_float(pr.y);
        float4 av = *(const float4*)(Ac + (size_t)pr.x*KK + 4*tid);
        ax0 += a*av.x; ax1 += a*av.y; ax2 += a*av.z; ax3 += a*av.w;
      }
      if (t<nB){
        int2 pr = spair[bB+t];
        float a = __int_as_float(pr.y);
        float4 av = *(const float4*)(Ac + (size_t)pr.x*KK + 4*tid);
        bx0 += a*av.x; bx1 += a*av.y; bx2 += a*av.z; bx3 += a*av.w;
      }
    }
    *(float4*)&U[g2*KK + 4*tid]     = make_float4(ax0,ax1,ax2,ax3);
    *(float4*)&U[(g2+1)*KK + 4*tid] = make_float4(bx0,bx1,bx2,bx3);
  }
  __syncthreads();
  // phase 2: adj[u0+g][w] = sum_q S[w,q] * U[g][q]; 8 b32 LDS reads (lanes spread by random q)
  for (int wb=0; wb<NN; wb+=1024){
    int w = wb + tid;
    int beg = srowptr[w], end = srowptr[w+1];
    float acc[8];
    #pragma unroll
    for (int g=0;g<8;g++) acc[g]=0.f;
    for (int i=beg;i<end;++i){
      int2 p = spair[i];
      float b = __int_as_float(p.y);
      int q = p.x;
      #pragma unroll
      for (int g=0;g<8;g++) acc[g] += b*U[g*KK+q];
    }
    #pragma unroll
    for (int g=0;g<8;g++)
      __builtin_nontemporal_store(acc[g], &adj[(size_t)(u0+g)*NN + w]);
  }
}

extern "C" void kernel_launch(void* const* d_in, const int* in_sizes, int n_in,
                              void* d_out, int out_size, void* d_ws, size_t ws_size,
                              hipStream_t stream){
  const float* nodes = (const float*)d_in[0];
  const int*   edges = (const int*)d_in[1];
  const float* w1=(const float*)d_in[3];  const float* b1=(const float*)d_in[4];
  const float* w2=(const float*)d_in[5];  const float* b2=(const float*)d_in[6];
  const float* w3=(const float*)d_in[7];  const float* b3=(const float*)d_in[8];
  const float* w4=(const float*)d_in[9];  const float* b4=(const float*)d_in[10];
  const float* w5=(const float*)d_in[11]; const float* b5=(const float*)d_in[12];
  const float* wq=(const float*)d_in[13]; const float* bq=(const float*)d_in[14];
  const float* att=(const float*)d_in[15];
  const float* lw1=(const float*)d_in[16]; const float* lb1=(const float*)d_in[17];
  const float* lw2=(const float*)d_in[18]; const float* lw3=(const float*)d_in[19];

  // ---- workspace layout (d_ws). First group is zero-initialized with ONE memset. ----
  char* ws = (char*)d_ws;
  size_t off = 0;
  auto take = [&](size_t bytes)->char*{
    char* p = ws + off;
    off = (off + bytes + 255) & ~(size_t)255;
    return p;
  };
  // zeroed group (contiguous):
  int*   deg     = (int*)  take((size_t)NN*4);
  int*   ecnt    = (int*)  take((size_t)NN*4);
  int*   scnt    = (int*)  take((size_t)NN*4);
  int*   ccnt    = (int*)  take((size_t)KK*4);
  int*   hist    = (int*)  take((size_t)NBIN*4);
  int*   ctr     = (int*)  take((size_t)4*4);     // [0]=winner ctr,[1]=tie ctr,[2]=B,[3]=nGT
  size_t zero_bytes = off;
  // rest:
  float* dis     = (float*)take((size_t)NN*4);
  int*   drowptr = (int*)  take((size_t)(NN+1)*4);
  int*   dcur    = (int*)  take((size_t)NN*4);
  int*   delist  = (int*)  take((size_t)ELn*4);
  float* alpha   = (float*)take((size_t)ELn*4);
  float* aq      = (float*)take((size_t)NN*4);
  float* ah      = (float*)take((size_t)NN*4);
  float* l1      = (float*)take((size_t)NN*4);
  float* l2      = (float*)take((size_t)NN*4);
  float* l3      = (float*)take((size_t)NN*4);
  float* fit     = (float*)take((size_t)NN*4);
  int*   inv     = (int*)  take((size_t)NN*4);
  int*   srowptr = (int*)  take((size_t)(NN+1)*4);
  int*   scur    = (int*)  take((size_t)NN*4);
  int2*  spair   = (int2*) take((size_t)ELn*8);
  int*   esptr   = (int*)  take((size_t)(NN+1)*4);
  int*   ecur    = (int*)  take((size_t)NN*4);
  int*   cptr    = (int*)  take((size_t)(KK+1)*4);
  int*   ccur    = (int*)  take((size_t)KK*4);
  unsigned long long* ties = (unsigned long long*)take((size_t)NN*8);
  float* Ac      = (float*)take((size_t)KK*KK*4);
  (void)ws_size; (void)in_sizes; (void)n_in; (void)out_size;

  // ---- big node buffers live in d_out's adj region (overwritten last by k_adj) ----
  float* out_x2 = (float*)d_out;                       // [NN,HH]
  float* adj    = (float*)d_out + (size_t)NN*HH;       // [NN,NN]
  float* BB = adj + 0*(size_t)NN*HH;  // h1 / h3
  float* BC = adj + 1*(size_t)NN*HH;  // h (post GCN2)
  float* BD = adj + 2*(size_t)NN*HH;  // h4
  float* BF = adj + 3*(size_t)NN*HH;  // cx
  float* BG = adj + 4*(size_t)NN*HH;  // x_out
  char*  sc2 = (char*)(adj + 5*(size_t)NN*HH);
  int*   desrc   = (int*)  sc2;                       sc2 += (size_t)ELn*4;
  int*   esdst   = (int*)  sc2;                       sc2 += (size_t)ELn*4;
  int*   srow_of = (int*)  sc2;                       sc2 += (size_t)ELn*4;
  int*   sdst_of = (int*)  sc2;                       sc2 += (size_t)ELn*4;
  int*   colu    = (int*)  sc2;                       sc2 += (size_t)ELn*4;
  float* cval    = (float*)sc2;                       sc2 += (size_t)ELn*4;

  const int EB = ELn/256;  // 544 exact

  // one memset zeroes all counters/hists
  hipMemsetAsync(deg, 0, zero_bytes, stream);

  // degree + CSR-by-dst + CSR-by-src (fused fills, fused scans)
  k_count<<<EB,256,0,stream>>>(edges,deg,ecnt);
  k_dis<<<NN/256,256,0,stream>>>(deg,dis);
  k_scan2<<<2,1024,0,stream>>>(deg,drowptr,dcur, ecnt,esptr,ecur);
  k_fill_both<<<EB,256,0,stream>>>(edges,dcur,ecur,delist,desrc,esdst);

  // GCN1, GCN2 (GCN2 also emits ah)
  k_layer<1,0><<<NN/8,256,0,stream>>>(nodes,desrc,drowptr,dis,w1,b1,nullptr,BB,nullptr);
  k_layer<1,1><<<NN/8,256,0,stream>>>(BB,desrc,drowptr,dis,w2,b2,att,BC,ah);

  // ASAP pooling
  k_pool<<<NN/8,256,0,stream>>>(BC,desrc,drowptr,wq,bq,att,aq);
  k_alpha<<<NN/4,256,0,stream>>>(delist,desrc,drowptr,aq,ah,alpha);
  k_cxle<<<NN,128,0,stream>>>(BC,delist,desrc,drowptr,alpha,lw1,lw2,lw3,BF,l1,l2,l3);
  k_fit<<<NN/4,256,0,stream>>>(desrc,drowptr,l1,l2,l3,lb1,fit,hist);

  // top-K select (set-exact, distributed)
  k_scanfind<<<1,1024,0,stream>>>(hist,ctr);
  k_assign<<<NN/256,256,0,stream>>>(fit,ctr,ctr,inv,ties);
  k_ties<<<1,1024,0,stream>>>(ctr,ctr,ties,inv);

  // S CSR (by src) + CSC (by col)
  k_scnt<<<EB,256,0,stream>>>(edges,inv,scnt);
  k_scan<8><<<1,1024,0,stream>>>(scnt,srowptr,scur);
  k_fill_s<<<EB,256,0,stream>>>(edges,inv,alpha,scur,spair,srow_of,sdst_of);
  k_col_cnt<<<EB,256,0,stream>>>(spair,srowptr,ccnt);
  k_scan<4><<<1,1024,0,stream>>>(ccnt,cptr,ccur);
  k_col_fill<<<EB,256,0,stream>>>(spair,srow_of,srowptr,ccur,colu,cval);

  // x_out = S @ xp (xp folded in), then GCN3/4/5 -> x2
  k_xout<<<NN,128,0,stream>>>(BF,fit,srowptr,spair,sdst_of,BG);
  k_layer<1,0><<<NN/8,256,0,stream>>>(BG,desrc,drowptr,dis,w3,b3,nullptr,BB,nullptr);
  k_layer<1,0><<<NN/8,256,0,stream>>>(BB,desrc,drowptr,dis,w4,b4,nullptr,BD,nullptr);
  k_layer<0,0><<<NN/8,256,0,stream>>>(BD,desrc,drowptr,dis,w5,b5,nullptr,out_x2,nullptr);

  // Ac = S^T A S (no global atomics), then adj_out = S Ac S^T
  k_ac2<<<KK,256,0,stream>>>(cptr,colu,cval,esptr,esdst,srowptr,spair,Ac);
  k_adj<<<NN/8,1024,0,stream>>>(Ac,srowptr,spair,adj);
}